// Round 1
// baseline (3324.261 us; speedup 1.0000x reference)
//
#include <hip/hip_runtime.h>
#include <hip/hip_bf16.h>

#define LRELU(v) ((v) > 0.0f ? (v) : 0.01f * (v))
#define EPS 0.1f

// ---------------------------------------------------------------------------
// K1: per-node feature MLP: x = lrelu(concat(lrelu(num@Wn+bn), lrelu(cat@Wc+bc)) @ Wtog + btog)
// wave-per-node (lane = channel). Also fuses al = x@att_l, ar = x@att_r reductions.
// ---------------------------------------------------------------------------
__global__ void k_feat(const float* __restrict__ num_prop,
                       const float* __restrict__ cat_prop,
                       const float* __restrict__ W_num, const float* __restrict__ b_num,
                       const float* __restrict__ W_cat, const float* __restrict__ b_cat,
                       const float* __restrict__ W_tog, const float* __restrict__ b_tog,
                       const float* __restrict__ att_l, const float* __restrict__ att_r,
                       float* __restrict__ x, float* __restrict__ al, float* __restrict__ ar,
                       int N)
{
    int w    = threadIdx.x >> 6;
    int lane = threadIdx.x & 63;
    int n    = blockIdx.x * 4 + w;
    bool act = (n < N);
    int nn   = act ? n : (N - 1);

    __shared__ float mid[4][64];

    float v;
    if (lane < 32) {
        float s = b_num[lane];
        const float* np_ = num_prop + (size_t)nn * 20;
        #pragma unroll
        for (int k = 0; k < 20; k++) s = fmaf(np_[k], W_num[k * 32 + lane], s);
        v = LRELU(s);
    } else {
        int c = lane - 32;
        float s = b_cat[c];
        const float* cp = cat_prop + (size_t)nn * 12;
        #pragma unroll
        for (int k = 0; k < 12; k++) s = fmaf(cp[k], W_cat[k * 32 + c], s);
        v = LRELU(s);
    }
    mid[w][lane] = v;
    __syncthreads();

    float s = b_tog[lane];
    #pragma unroll 8
    for (int k = 0; k < 64; k++) s = fmaf(mid[w][k], W_tog[k * 64 + lane], s);
    float xv = LRELU(s);

    float pl = xv * att_l[lane];
    float pr = xv * att_r[lane];
    #pragma unroll
    for (int off = 32; off > 0; off >>= 1) {
        pl += __shfl_down(pl, off);
        pr += __shfl_down(pr, off);
    }
    if (act) {
        x[(size_t)n * 64 + lane] = xv;
        if (lane == 0) { al[n] = pl; ar[n] = pr; }
    }
}

// ---------------------------------------------------------------------------
// K2: in-degree histogram over dst (self-loop added in k_dinv)
// ---------------------------------------------------------------------------
__global__ void k_deg(const int* __restrict__ dst, int* __restrict__ deg, int E)
{
    int e = blockIdx.x * blockDim.x + threadIdx.x;
    if (e < E) atomicAdd(&deg[dst[e]], 1);
}

__global__ void k_dinv(const int* __restrict__ deg, float* __restrict__ dinv, int N)
{
    int i = blockIdx.x * blockDim.x + threadIdx.x;
    if (i < N) dinv[i] = 1.0f / sqrtf((float)deg[i] + 1.0f);  // +1 self-loop
}

// ---------------------------------------------------------------------------
// K3: per-edge attention coefficient alpha = tanh(al[s]+ar[d]) * dinv[s]*dinv[d]
// ---------------------------------------------------------------------------
__global__ void k_alpha(const int* __restrict__ src, const int* __restrict__ dst,
                        const float* __restrict__ al, const float* __restrict__ ar,
                        const float* __restrict__ dinv, float* __restrict__ alpha, int E)
{
    int e = blockIdx.x * blockDim.x + threadIdx.x;
    if (e < E) {
        int s = src[e], d = dst[e];
        alpha[e] = tanhf(al[s] + ar[d]) * dinv[s] * dinv[d];
    }
}

// ---------------------------------------------------------------------------
// K4: edge scatter: agg[dst] += h[src] * alpha.  16 threads per edge, float4/thread.
// ---------------------------------------------------------------------------
__global__ void k_scatter(const int* __restrict__ src, const int* __restrict__ dst,
                          const float* __restrict__ alpha, const float* __restrict__ h,
                          float* __restrict__ agg, int E)
{
    long long t = (long long)blockIdx.x * blockDim.x + threadIdx.x;
    int e = (int)(t >> 4);
    if (e >= E) return;
    int c = ((int)t & 15) << 2;
    int s = src[e], d = dst[e];
    float a = alpha[e];
    const float4 hv = *(const float4*)(h + (size_t)s * 64 + c);
    float* base = agg + (size_t)d * 64 + c;
    atomicAdd(base + 0, hv.x * a);
    atomicAdd(base + 1, hv.y * a);
    atomicAdd(base + 2, hv.z * a);
    atomicAdd(base + 3, hv.w * a);
}

// ---------------------------------------------------------------------------
// K5: finalize layer 1: h1 = agg + (self_alpha + EPS) * x   (h == h0 == x here)
//     fuses al2/ar2 = h1 @ att_{l,r} reductions. wave-per-node.
// ---------------------------------------------------------------------------
__global__ void k_fin1(const float* __restrict__ agg, const float* __restrict__ x,
                       const float* __restrict__ al, const float* __restrict__ ar,
                       const float* __restrict__ dinv,
                       const float* __restrict__ att_l, const float* __restrict__ att_r,
                       float* __restrict__ h1, float* __restrict__ al2, float* __restrict__ ar2,
                       int N)
{
    int w    = threadIdx.x >> 6;
    int lane = threadIdx.x & 63;
    int n    = blockIdx.x * 4 + w;
    bool act = (n < N);
    int nn   = act ? n : (N - 1);

    float di    = dinv[nn];
    float selfa = tanhf(al[nn] + ar[nn]) * di * di;
    float xv    = x[(size_t)nn * 64 + lane];
    float v     = agg[(size_t)nn * 64 + lane] + (selfa + EPS) * xv;

    float pl = v * att_l[lane];
    float pr = v * att_r[lane];
    #pragma unroll
    for (int off = 32; off > 0; off >>= 1) {
        pl += __shfl_down(pl, off);
        pr += __shfl_down(pr, off);
    }
    if (act) {
        h1[(size_t)n * 64 + lane] = v;
        if (lane == 0) { al2[n] = pl; ar2[n] = pr; }
    }
}

// ---------------------------------------------------------------------------
// K6: finalize layer 2 + abs-smooth: x2 = sqrt((agg + selfa*h1 + EPS*x)^2 + 1e-8)
//     written in place over agg. thread-per-element.
// ---------------------------------------------------------------------------
__global__ void k_fin2(float* __restrict__ agg,
                       const float* __restrict__ h1, const float* __restrict__ x,
                       const float* __restrict__ al2, const float* __restrict__ ar2,
                       const float* __restrict__ dinv, int N)
{
    size_t i = (size_t)blockIdx.x * blockDim.x + threadIdx.x;
    if (i >= (size_t)N * 64) return;
    int n = (int)(i >> 6);
    float di    = dinv[n];
    float selfa = tanhf(al2[n] + ar2[n]) * di * di;
    float v = agg[i] + selfa * h1[i] + EPS * x[i];
    agg[i] = sqrtf(v * v + 1e-8f);
}

// ---------------------------------------------------------------------------
// K7: per-user CSR segment sum: x3[u] = sum_{n in [offs[u], offs[u+1])} x2[n]
//     one wave per user, lane = channel (coalesced 256B rows).
// ---------------------------------------------------------------------------
__global__ void k_usersum(const float* __restrict__ x2, const int* __restrict__ offs,
                          float* __restrict__ x3, int U)
{
    int u    = blockIdx.x;
    int lane = threadIdx.x;
    if (u >= U) return;
    int s = offs[u], e = offs[u + 1];
    float acc = 0.0f;
    for (int n = s; n < e; n++) acc += x2[(size_t)n * 64 + lane];
    x3[(size_t)u * 64 + lane] = acc;
}

// ---------------------------------------------------------------------------
// K8: head: out = lrelu(x3[re_index] @ W_f1 + b_f1) @ W_lab + b_lab
//     thread-per-user; weights are wave-uniform loads (scalar-cached).
// ---------------------------------------------------------------------------
__global__ void k_head(const float* __restrict__ x3, const int* __restrict__ re_index,
                       const float* __restrict__ W_f1, const float* __restrict__ b_f1,
                       const float* __restrict__ W_lab, const float* __restrict__ b_lab,
                       float* __restrict__ out, int U)
{
    int u = blockIdx.x * blockDim.x + threadIdx.x;
    if (u >= U) return;
    int r = re_index[u];
    const float* y = x3 + (size_t)r * 64;
    float yv[64];
    #pragma unroll
    for (int k = 0; k < 64; k++) yv[k] = y[k];
    float o0 = b_lab[0], o1 = b_lab[1];
    for (int j = 0; j < 32; j++) {
        float s = b_f1[j];
        #pragma unroll 8
        for (int k = 0; k < 64; k++) s = fmaf(yv[k], W_f1[k * 32 + j], s);
        s = LRELU(s);
        o0 = fmaf(s, W_lab[j * 2 + 0], o0);
        o1 = fmaf(s, W_lab[j * 2 + 1], o1);
    }
    out[(size_t)u * 2 + 0] = o0;
    out[(size_t)u * 2 + 1] = o1;
}

// ---------------------------------------------------------------------------
extern "C" void kernel_launch(void* const* d_in, const int* in_sizes, int n_in,
                              void* d_out, int out_size, void* d_ws, size_t ws_size,
                              hipStream_t stream)
{
    const float* num_prop = (const float*)d_in[0];
    const float* cat_prop = (const float*)d_in[1];
    const int*   offs     = (const int*)d_in[2];
    const int*   edge     = (const int*)d_in[3];
    const int*   re_index = (const int*)d_in[4];
    const float* W_num    = (const float*)d_in[5];
    const float* b_num    = (const float*)d_in[6];
    const float* W_cat    = (const float*)d_in[7];
    const float* b_cat    = (const float*)d_in[8];
    const float* W_tog    = (const float*)d_in[9];
    const float* b_tog    = (const float*)d_in[10];
    const float* att_l    = (const float*)d_in[11];
    const float* att_r    = (const float*)d_in[12];
    const float* W_f1     = (const float*)d_in[13];
    const float* b_f1     = (const float*)d_in[14];
    const float* W_lab    = (const float*)d_in[15];
    const float* b_lab    = (const float*)d_in[16];

    const int N = in_sizes[0] / 20;
    const int E = in_sizes[3] / 2;
    const int U = in_sizes[4];

    const int* src = edge;       // edge_index[0]
    const int* dst = edge + E;   // edge_index[1]

    // workspace carve-up (floats)
    float* ws = (float*)d_ws;
    size_t off = 0;
    float* x    = ws + off; off += (size_t)N * 64;
    float* h1   = ws + off; off += (size_t)N * 64;
    float* B    = ws + off; off += (size_t)N * 64;   // agg buffer (reused both layers, ends as x2)
    float* al   = ws + off; off += N;
    float* ar   = ws + off; off += N;
    float* al2  = ws + off; off += N;
    float* ar2  = ws + off; off += N;
    float* dinv = ws + off; off += N;
    float* alpha= ws + off; off += E;
    float* x3   = ws + off; off += (size_t)U * 64;
    int*   deg  = (int*)(ws + off); off += N;

    hipMemsetAsync(deg, 0, (size_t)N * 4, stream);
    hipMemsetAsync(B,   0, (size_t)N * 64 * 4, stream);

    const int nbN4 = (N + 3) / 4;                    // wave-per-node kernels, 4 nodes/block
    const long long st = (long long)E * 16;          // scatter work items

    k_feat<<<nbN4, 256, 0, stream>>>(num_prop, cat_prop, W_num, b_num, W_cat, b_cat,
                                     W_tog, b_tog, att_l, att_r, x, al, ar, N);
    k_deg<<<(E + 255) / 256, 256, 0, stream>>>(dst, deg, E);
    k_dinv<<<(N + 255) / 256, 256, 0, stream>>>(deg, dinv, N);

    // ---- FAConv layer 1 (h = h0 = x) ----
    k_alpha<<<(E + 255) / 256, 256, 0, stream>>>(src, dst, al, ar, dinv, alpha, E);
    k_scatter<<<(int)((st + 255) / 256), 256, 0, stream>>>(src, dst, alpha, x, B, E);
    k_fin1<<<nbN4, 256, 0, stream>>>(B, x, al, ar, dinv, att_l, att_r, h1, al2, ar2, N);

    // ---- FAConv layer 2 (h = h1, h0 = x) ----
    hipMemsetAsync(B, 0, (size_t)N * 64 * 4, stream);
    k_alpha<<<(E + 255) / 256, 256, 0, stream>>>(src, dst, al2, ar2, dinv, alpha, E);
    k_scatter<<<(int)((st + 255) / 256), 256, 0, stream>>>(src, dst, alpha, h1, B, E);
    k_fin2<<<(int)(((size_t)N * 64 + 255) / 256), 256, 0, stream>>>(B, h1, x, al2, ar2, dinv, N);

    // ---- per-user pooling + head ----
    k_usersum<<<U, 64, 0, stream>>>(B, offs, x3, U);
    k_head<<<(U + 255) / 256, 256, 0, stream>>>(x3, re_index, W_f1, b_f1, W_lab, b_lab,
                                                (float*)d_out, U);
}

// Round 2
// 1076.155 us; speedup vs baseline: 3.0890x; 3.0890x over previous
//
#include <hip/hip_runtime.h>
#include <hip/hip_bf16.h>

#define LRELU(v) ((v) > 0.0f ? (v) : 0.01f * (v))
#define EPS 0.1f

// ---------------------------------------------------------------------------
// K1: per-node feature MLP: x = lrelu(concat(lrelu(num@Wn+bn), lrelu(cat@Wc+bc)) @ Wtog + btog)
// wave-per-node (lane = channel). Fuses al = x@att_l, ar = x@att_r reductions.
// ---------------------------------------------------------------------------
__global__ void k_feat(const float* __restrict__ num_prop,
                       const float* __restrict__ cat_prop,
                       const float* __restrict__ W_num, const float* __restrict__ b_num,
                       const float* __restrict__ W_cat, const float* __restrict__ b_cat,
                       const float* __restrict__ W_tog, const float* __restrict__ b_tog,
                       const float* __restrict__ att_l, const float* __restrict__ att_r,
                       float* __restrict__ x, float* __restrict__ al, float* __restrict__ ar,
                       int N)
{
    int w    = threadIdx.x >> 6;
    int lane = threadIdx.x & 63;
    int n    = blockIdx.x * 4 + w;
    bool act = (n < N);
    int nn   = act ? n : (N - 1);

    __shared__ float mid[4][64];

    float v;
    if (lane < 32) {
        float s = b_num[lane];
        const float* np_ = num_prop + (size_t)nn * 20;
        #pragma unroll
        for (int k = 0; k < 20; k++) s = fmaf(np_[k], W_num[k * 32 + lane], s);
        v = LRELU(s);
    } else {
        int c = lane - 32;
        float s = b_cat[c];
        const float* cp = cat_prop + (size_t)nn * 12;
        #pragma unroll
        for (int k = 0; k < 12; k++) s = fmaf(cp[k], W_cat[k * 32 + c], s);
        v = LRELU(s);
    }
    mid[w][lane] = v;
    __syncthreads();

    float s = b_tog[lane];
    #pragma unroll 8
    for (int k = 0; k < 64; k++) s = fmaf(mid[w][k], W_tog[k * 64 + lane], s);
    float xv = LRELU(s);

    float pl = xv * att_l[lane];
    float pr = xv * att_r[lane];
    #pragma unroll
    for (int off = 32; off > 0; off >>= 1) {
        pl += __shfl_down(pl, off);
        pr += __shfl_down(pr, off);
    }
    if (act) {
        x[(size_t)n * 64 + lane] = xv;
        if (lane == 0) { al[n] = pl; ar[n] = pr; }
    }
}

// ---------------------------------------------------------------------------
// K2: in-degree histogram over dst (self-loop folded in analytically later)
// ---------------------------------------------------------------------------
__global__ void k_deg(const int* __restrict__ dst, int* __restrict__ deg, int E)
{
    int e = blockIdx.x * blockDim.x + threadIdx.x;
    if (e < E) atomicAdd(&deg[dst[e]], 1);
}

// ---------------------------------------------------------------------------
// CSR build: hierarchical exclusive scan of deg -> row_start, then atomic fill.
// ---------------------------------------------------------------------------
__global__ void k_scan1(const int* __restrict__ deg, int* __restrict__ row_start,
                        int* __restrict__ blockSums, int N)
{
    __shared__ int sh[1024];
    int tid = threadIdx.x;
    int i = blockIdx.x * 1024 + tid;
    int v = (i < N) ? deg[i] : 0;
    sh[tid] = v;
    __syncthreads();
    #pragma unroll
    for (int off = 1; off < 1024; off <<= 1) {
        int t = (tid >= off) ? sh[tid - off] : 0;
        __syncthreads();
        sh[tid] += t;
        __syncthreads();
    }
    if (i < N) row_start[i] = sh[tid] - v;          // exclusive within block
    if (tid == 1023) blockSums[blockIdx.x] = sh[1023];
}

__global__ void k_scan2(int* __restrict__ blockSums, int nb)
{
    __shared__ int sh[256];
    int tid = threadIdx.x;
    int v = (tid < nb) ? blockSums[tid] : 0;
    sh[tid] = v;
    __syncthreads();
    #pragma unroll
    for (int off = 1; off < 256; off <<= 1) {
        int t = (tid >= off) ? sh[tid - off] : 0;
        __syncthreads();
        sh[tid] += t;
        __syncthreads();
    }
    if (tid < nb) blockSums[tid] = sh[tid] - v;     // exclusive
}

// row_start += block offset; init cursor; dinv = rsqrt(deg+1)
__global__ void k_scan3(int* __restrict__ row_start, const int* __restrict__ blockSums,
                        int* __restrict__ cursor, const int* __restrict__ deg,
                        float* __restrict__ dinv, int N)
{
    int i = blockIdx.x * blockDim.x + threadIdx.x;
    if (i >= N) return;
    int rs = row_start[i] + blockSums[i >> 10];
    row_start[i] = rs;
    cursor[i]    = rs;
    dinv[i]      = 1.0f / sqrtf((float)deg[i] + 1.0f);   // +1 self-loop
}

__global__ void k_fill(const int* __restrict__ src, const int* __restrict__ dst,
                       int* __restrict__ cursor, int* __restrict__ srcs, int E)
{
    int e = blockIdx.x * blockDim.x + threadIdx.x;
    if (e >= E) return;
    int d = dst[e];
    int p = atomicAdd(&cursor[d], 1);
    srcs[p] = src[e];
}

// ---------------------------------------------------------------------------
// K5: gather layer 1 (h = h0 = x), fused finalize:
//     h1[n] = sum_e alpha_e * x[src_e] + (self_alpha + EPS) * x[n]
//     + fused al2/ar2 = h1 @ att_{l,r}.  wave-per-node, lane = channel.
// ---------------------------------------------------------------------------
__global__ void k_gather1(const int* __restrict__ srcs, const int* __restrict__ row_start,
                          const int* __restrict__ deg,
                          const float* __restrict__ x,
                          const float* __restrict__ al, const float* __restrict__ ar,
                          const float* __restrict__ dinv,
                          const float* __restrict__ att_l, const float* __restrict__ att_r,
                          float* __restrict__ h1, float* __restrict__ al2, float* __restrict__ ar2,
                          int N)
{
    int w    = threadIdx.x >> 6;
    int lane = threadIdx.x & 63;
    int n    = blockIdx.x * 4 + w;
    if (n >= N) return;

    int   s0  = row_start[n];
    int   cnt = deg[n];
    float di  = dinv[n];
    float arn = ar[n];

    float acc = 0.0f;
    for (int j = 0; j < cnt; j++) {
        int   s = srcs[s0 + j];
        float a = tanhf(al[s] + arn) * dinv[s] * di;
        acc = fmaf(x[(size_t)s * 64 + lane], a, acc);
    }
    float selfa = tanhf(al[n] + arn) * di * di;
    float v = acc + (selfa + EPS) * x[(size_t)n * 64 + lane];

    float pl = v * att_l[lane];
    float pr = v * att_r[lane];
    #pragma unroll
    for (int off = 32; off > 0; off >>= 1) {
        pl += __shfl_down(pl, off);
        pr += __shfl_down(pr, off);
    }
    h1[(size_t)n * 64 + lane] = v;
    if (lane == 0) { al2[n] = pl; ar2[n] = pr; }
}

// ---------------------------------------------------------------------------
// K6: gather layer 2 (h = h1, h0 = x), fused finalize + abs-smooth:
//     x2[n] = sqrt((sum_e alpha_e*h1[src_e] + selfa*h1[n] + EPS*x[n])^2 + 1e-8)
// ---------------------------------------------------------------------------
__global__ void k_gather2(const int* __restrict__ srcs, const int* __restrict__ row_start,
                          const int* __restrict__ deg,
                          const float* __restrict__ h1, const float* __restrict__ x,
                          const float* __restrict__ al2, const float* __restrict__ ar2,
                          const float* __restrict__ dinv,
                          float* __restrict__ x2, int N)
{
    int w    = threadIdx.x >> 6;
    int lane = threadIdx.x & 63;
    int n    = blockIdx.x * 4 + w;
    if (n >= N) return;

    int   s0  = row_start[n];
    int   cnt = deg[n];
    float di  = dinv[n];
    float arn = ar2[n];

    float acc = 0.0f;
    for (int j = 0; j < cnt; j++) {
        int   s = srcs[s0 + j];
        float a = tanhf(al2[s] + arn) * dinv[s] * di;
        acc = fmaf(h1[(size_t)s * 64 + lane], a, acc);
    }
    float selfa = tanhf(al2[n] + arn) * di * di;
    float v = acc + selfa * h1[(size_t)n * 64 + lane] + EPS * x[(size_t)n * 64 + lane];
    x2[(size_t)n * 64 + lane] = sqrtf(v * v + 1e-8f);
}

// ---------------------------------------------------------------------------
// K7: per-user CSR segment sum: x3[u] = sum_{n in [offs[u], offs[u+1])} x2[n]
// ---------------------------------------------------------------------------
__global__ void k_usersum(const float* __restrict__ x2, const int* __restrict__ offs,
                          float* __restrict__ x3, int U)
{
    int u    = blockIdx.x;
    int lane = threadIdx.x;
    if (u >= U) return;
    int s = offs[u], e = offs[u + 1];
    float acc = 0.0f;
    for (int n = s; n < e; n++) acc += x2[(size_t)n * 64 + lane];
    x3[(size_t)u * 64 + lane] = acc;
}

// ---------------------------------------------------------------------------
// K8: head: out = lrelu(x3[re_index] @ W_f1 + b_f1) @ W_lab + b_lab
// ---------------------------------------------------------------------------
__global__ void k_head(const float* __restrict__ x3, const int* __restrict__ re_index,
                       const float* __restrict__ W_f1, const float* __restrict__ b_f1,
                       const float* __restrict__ W_lab, const float* __restrict__ b_lab,
                       float* __restrict__ out, int U)
{
    int u = blockIdx.x * blockDim.x + threadIdx.x;
    if (u >= U) return;
    int r = re_index[u];
    const float* y = x3 + (size_t)r * 64;
    float yv[64];
    #pragma unroll
    for (int k = 0; k < 64; k++) yv[k] = y[k];
    float o0 = b_lab[0], o1 = b_lab[1];
    for (int j = 0; j < 32; j++) {
        float s = b_f1[j];
        #pragma unroll 8
        for (int k = 0; k < 64; k++) s = fmaf(yv[k], W_f1[k * 32 + j], s);
        s = LRELU(s);
        o0 = fmaf(s, W_lab[j * 2 + 0], o0);
        o1 = fmaf(s, W_lab[j * 2 + 1], o1);
    }
    out[(size_t)u * 2 + 0] = o0;
    out[(size_t)u * 2 + 1] = o1;
}

// ---------------------------------------------------------------------------
extern "C" void kernel_launch(void* const* d_in, const int* in_sizes, int n_in,
                              void* d_out, int out_size, void* d_ws, size_t ws_size,
                              hipStream_t stream)
{
    const float* num_prop = (const float*)d_in[0];
    const float* cat_prop = (const float*)d_in[1];
    const int*   offs     = (const int*)d_in[2];
    const int*   edge     = (const int*)d_in[3];
    const int*   re_index = (const int*)d_in[4];
    const float* W_num    = (const float*)d_in[5];
    const float* b_num    = (const float*)d_in[6];
    const float* W_cat    = (const float*)d_in[7];
    const float* b_cat    = (const float*)d_in[8];
    const float* W_tog    = (const float*)d_in[9];
    const float* b_tog    = (const float*)d_in[10];
    const float* att_l    = (const float*)d_in[11];
    const float* att_r    = (const float*)d_in[12];
    const float* W_f1     = (const float*)d_in[13];
    const float* b_f1     = (const float*)d_in[14];
    const float* W_lab    = (const float*)d_in[15];
    const float* b_lab    = (const float*)d_in[16];

    const int N = in_sizes[0] / 20;
    const int E = in_sizes[3] / 2;
    const int U = in_sizes[4];

    const int* src = edge;       // edge_index[0]
    const int* dst = edge + E;   // edge_index[1]

    // workspace carve-up (4-byte units)
    float* ws = (float*)d_ws;
    size_t off = 0;
    float* x    = ws + off; off += (size_t)N * 64;
    float* h1   = ws + off; off += (size_t)N * 64;
    float* B    = ws + off; off += (size_t)N * 64;   // x2
    float* al   = ws + off; off += N;
    float* ar   = ws + off; off += N;
    float* al2  = ws + off; off += N;
    float* ar2  = ws + off; off += N;
    float* dinv = ws + off; off += N;
    float* x3   = ws + off; off += (size_t)U * 64;
    int*   deg       = (int*)(ws + off); off += N;
    int*   row_start = (int*)(ws + off); off += N;
    int*   cursor    = (int*)(ws + off); off += N;
    int*   srcs      = (int*)(ws + off); off += E;
    int*   blockSums = (int*)(ws + off); off += 256;

    hipMemsetAsync(deg, 0, (size_t)N * 4, stream);

    const int nbN4    = (N + 3) / 4;          // wave-per-node kernels, 4 nodes/block
    const int nbScan  = (N + 1023) / 1024;    // <= 256 required by k_scan2

    k_feat<<<nbN4, 256, 0, stream>>>(num_prop, cat_prop, W_num, b_num, W_cat, b_cat,
                                     W_tog, b_tog, att_l, att_r, x, al, ar, N);
    k_deg<<<(E + 255) / 256, 256, 0, stream>>>(dst, deg, E);

    // CSR build (layer-independent, reused by both gathers)
    k_scan1<<<nbScan, 1024, 0, stream>>>(deg, row_start, blockSums, N);
    k_scan2<<<1, 256, 0, stream>>>(blockSums, nbScan);
    k_scan3<<<(N + 255) / 256, 256, 0, stream>>>(row_start, blockSums, cursor, deg, dinv, N);
    k_fill<<<(E + 255) / 256, 256, 0, stream>>>(src, dst, cursor, srcs, E);

    // ---- FAConv layer 1 (h = h0 = x), fused finalize ----
    k_gather1<<<nbN4, 256, 0, stream>>>(srcs, row_start, deg, x, al, ar, dinv,
                                        att_l, att_r, h1, al2, ar2, N);

    // ---- FAConv layer 2 (h = h1, h0 = x), fused finalize + abs ----
    k_gather2<<<nbN4, 256, 0, stream>>>(srcs, row_start, deg, h1, x, al2, ar2, dinv, B, N);

    // ---- per-user pooling + head ----
    k_usersum<<<U, 64, 0, stream>>>(B, offs, x3, U);
    k_head<<<(U + 255) / 256, 256, 0, stream>>>(x3, re_index, W_f1, b_f1, W_lab, b_lab,
                                                (float*)d_out, U);
}

// Round 3
// 828.711 us; speedup vs baseline: 4.0114x; 1.2986x over previous
//
#include <hip/hip_runtime.h>
#include <hip/hip_bf16.h>

#define LRELU(v) ((v) > 0.0f ? (v) : 0.01f * (v))
#define EPS 0.1f

// ---------------------------------------------------------------------------
// K1: per-node feature MLP, fused al/ar attention dot products. wave-per-node.
// ---------------------------------------------------------------------------
__global__ void k_feat(const float* __restrict__ num_prop,
                       const float* __restrict__ cat_prop,
                       const float* __restrict__ W_num, const float* __restrict__ b_num,
                       const float* __restrict__ W_cat, const float* __restrict__ b_cat,
                       const float* __restrict__ W_tog, const float* __restrict__ b_tog,
                       const float* __restrict__ att_l, const float* __restrict__ att_r,
                       float* __restrict__ x, float* __restrict__ al, float* __restrict__ ar,
                       int N)
{
    int w    = threadIdx.x >> 6;
    int lane = threadIdx.x & 63;
    int n    = blockIdx.x * 4 + w;
    bool act = (n < N);
    int nn   = act ? n : (N - 1);

    __shared__ float mid[4][64];

    float v;
    if (lane < 32) {
        float s = b_num[lane];
        const float* np_ = num_prop + (size_t)nn * 20;
        #pragma unroll
        for (int k = 0; k < 20; k++) s = fmaf(np_[k], W_num[k * 32 + lane], s);
        v = LRELU(s);
    } else {
        int c = lane - 32;
        float s = b_cat[c];
        const float* cp = cat_prop + (size_t)nn * 12;
        #pragma unroll
        for (int k = 0; k < 12; k++) s = fmaf(cp[k], W_cat[k * 32 + c], s);
        v = LRELU(s);
    }
    mid[w][lane] = v;
    __syncthreads();

    float s = b_tog[lane];
    #pragma unroll 8
    for (int k = 0; k < 64; k++) s = fmaf(mid[w][k], W_tog[k * 64 + lane], s);
    float xv = LRELU(s);

    float pl = xv * att_l[lane];
    float pr = xv * att_r[lane];
    #pragma unroll
    for (int off = 32; off > 0; off >>= 1) {
        pl += __shfl_down(pl, off);
        pr += __shfl_down(pr, off);
    }
    if (act) {
        x[(size_t)n * 64 + lane] = xv;
        if (lane == 0) { al[n] = pl; ar[n] = pr; }
    }
}

// ---------------------------------------------------------------------------
// K2: in-degree histogram over dst (self-loop folded in analytically later)
// ---------------------------------------------------------------------------
__global__ void k_deg(const int* __restrict__ dst, int* __restrict__ deg, int E)
{
    int e = blockIdx.x * blockDim.x + threadIdx.x;
    if (e < E) atomicAdd(&deg[dst[e]], 1);
}

// ---------------------------------------------------------------------------
// CSR build: hierarchical exclusive scan of deg -> row_start, then atomic fill.
// ---------------------------------------------------------------------------
__global__ void k_scan1(const int* __restrict__ deg, int* __restrict__ row_start,
                        int* __restrict__ blockSums, int N)
{
    __shared__ int sh[1024];
    int tid = threadIdx.x;
    int i = blockIdx.x * 1024 + tid;
    int v = (i < N) ? deg[i] : 0;
    sh[tid] = v;
    __syncthreads();
    #pragma unroll
    for (int off = 1; off < 1024; off <<= 1) {
        int t = (tid >= off) ? sh[tid - off] : 0;
        __syncthreads();
        sh[tid] += t;
        __syncthreads();
    }
    if (i < N) row_start[i] = sh[tid] - v;          // exclusive within block
    if (tid == 1023) blockSums[blockIdx.x] = sh[1023];
}

__global__ void k_scan2(int* __restrict__ blockSums, int nb)
{
    __shared__ int sh[256];
    int tid = threadIdx.x;
    int v = (tid < nb) ? blockSums[tid] : 0;
    sh[tid] = v;
    __syncthreads();
    #pragma unroll
    for (int off = 1; off < 256; off <<= 1) {
        int t = (tid >= off) ? sh[tid - off] : 0;
        __syncthreads();
        sh[tid] += t;
        __syncthreads();
    }
    if (tid < nb) blockSums[tid] = sh[tid] - v;     // exclusive
}

// row_start += block offset; init cursor; dinv = rsqrt(deg+1)
__global__ void k_scan3(int* __restrict__ row_start, const int* __restrict__ blockSums,
                        int* __restrict__ cursor, const int* __restrict__ deg,
                        float* __restrict__ dinv, int N)
{
    int i = blockIdx.x * blockDim.x + threadIdx.x;
    if (i >= N) return;
    int rs = row_start[i] + blockSums[i >> 10];
    row_start[i] = rs;
    cursor[i]    = rs;
    dinv[i]      = 1.0f / sqrtf((float)deg[i] + 1.0f);   // +1 self-loop
}

// fill CSR-ordered (src,dst) pairs: one 8B scattered store per edge
__global__ void k_fill(const int* __restrict__ src, const int* __restrict__ dst,
                       int* __restrict__ cursor, int2* __restrict__ meta0, int E)
{
    int e = blockIdx.x * blockDim.x + threadIdx.x;
    if (e >= E) return;
    int d = dst[e];
    int p = atomicAdd(&cursor[d], 1);
    meta0[p] = make_int2(src[e], d);
}

// ---------------------------------------------------------------------------
// K4: per-edge alpha (edge-parallel, CSR order): meta[p] = {src, tanh(al[s]+ar[d])*dinv[s]*dinv[d]}
// Massive parallelism hides the random al/ar/dinv latency.
// ---------------------------------------------------------------------------
__global__ void k_alpha(const int2* __restrict__ meta0,
                        const float* __restrict__ al, const float* __restrict__ ar,
                        const float* __restrict__ dinv, int2* __restrict__ meta, int E)
{
    int p = blockIdx.x * blockDim.x + threadIdx.x;
    if (p >= E) return;
    int2 m = meta0[p];
    float a = tanhf(al[m.x] + ar[m.y]) * dinv[m.x] * dinv[m.y];
    meta[p] = make_int2(m.x, __float_as_int(a));
}

// ---------------------------------------------------------------------------
// K5: gather layer 1 (h = h0 = x), fused finalize + al2/ar2 reductions.
// wave-per-node, lane = channel. Unrolled x4: 4 independent row loads in flight.
// ---------------------------------------------------------------------------
__global__ void k_gather1(const int2* __restrict__ meta, const int* __restrict__ row_start,
                          const int* __restrict__ deg,
                          const float* __restrict__ x,
                          const float* __restrict__ al, const float* __restrict__ ar,
                          const float* __restrict__ dinv,
                          const float* __restrict__ att_l, const float* __restrict__ att_r,
                          float* __restrict__ h1, float* __restrict__ al2, float* __restrict__ ar2,
                          int N)
{
    int w    = threadIdx.x >> 6;
    int lane = threadIdx.x & 63;
    int n    = blockIdx.x * 4 + w;
    if (n >= N) return;

    int s0  = row_start[n];
    int cnt = deg[n];

    float acc = 0.0f;
    int j = 0;
    for (; j + 4 <= cnt; j += 4) {
        int2 m0 = meta[s0 + j + 0];
        int2 m1 = meta[s0 + j + 1];
        int2 m2 = meta[s0 + j + 2];
        int2 m3 = meta[s0 + j + 3];
        float v0 = x[(size_t)m0.x * 64 + lane];
        float v1 = x[(size_t)m1.x * 64 + lane];
        float v2 = x[(size_t)m2.x * 64 + lane];
        float v3 = x[(size_t)m3.x * 64 + lane];
        acc = fmaf(v0, __int_as_float(m0.y), acc);
        acc = fmaf(v1, __int_as_float(m1.y), acc);
        acc = fmaf(v2, __int_as_float(m2.y), acc);
        acc = fmaf(v3, __int_as_float(m3.y), acc);
    }
    for (; j < cnt; j++) {
        int2 m = meta[s0 + j];
        acc = fmaf(x[(size_t)m.x * 64 + lane], __int_as_float(m.y), acc);
    }

    float di    = dinv[n];
    float selfa = tanhf(al[n] + ar[n]) * di * di;
    float v     = acc + (selfa + EPS) * x[(size_t)n * 64 + lane];

    float pl = v * att_l[lane];
    float pr = v * att_r[lane];
    #pragma unroll
    for (int off = 32; off > 0; off >>= 1) {
        pl += __shfl_down(pl, off);
        pr += __shfl_down(pr, off);
    }
    h1[(size_t)n * 64 + lane] = v;
    if (lane == 0) { al2[n] = pl; ar2[n] = pr; }
}

// ---------------------------------------------------------------------------
// K6: gather layer 2 (h = h1, h0 = x), fused finalize + abs-smooth.
// ---------------------------------------------------------------------------
__global__ void k_gather2(const int2* __restrict__ meta, const int* __restrict__ row_start,
                          const int* __restrict__ deg,
                          const float* __restrict__ h1, const float* __restrict__ x,
                          const float* __restrict__ al2, const float* __restrict__ ar2,
                          const float* __restrict__ dinv,
                          float* __restrict__ x2, int N)
{
    int w    = threadIdx.x >> 6;
    int lane = threadIdx.x & 63;
    int n    = blockIdx.x * 4 + w;
    if (n >= N) return;

    int s0  = row_start[n];
    int cnt = deg[n];

    float acc = 0.0f;
    int j = 0;
    for (; j + 4 <= cnt; j += 4) {
        int2 m0 = meta[s0 + j + 0];
        int2 m1 = meta[s0 + j + 1];
        int2 m2 = meta[s0 + j + 2];
        int2 m3 = meta[s0 + j + 3];
        float v0 = h1[(size_t)m0.x * 64 + lane];
        float v1 = h1[(size_t)m1.x * 64 + lane];
        float v2 = h1[(size_t)m2.x * 64 + lane];
        float v3 = h1[(size_t)m3.x * 64 + lane];
        acc = fmaf(v0, __int_as_float(m0.y), acc);
        acc = fmaf(v1, __int_as_float(m1.y), acc);
        acc = fmaf(v2, __int_as_float(m2.y), acc);
        acc = fmaf(v3, __int_as_float(m3.y), acc);
    }
    for (; j < cnt; j++) {
        int2 m = meta[s0 + j];
        acc = fmaf(h1[(size_t)m.x * 64 + lane], __int_as_float(m.y), acc);
    }

    float di    = dinv[n];
    float selfa = tanhf(al2[n] + ar2[n]) * di * di;
    float v = acc + selfa * h1[(size_t)n * 64 + lane] + EPS * x[(size_t)n * 64 + lane];
    x2[(size_t)n * 64 + lane] = sqrtf(v * v + 1e-8f);
}

// ---------------------------------------------------------------------------
// K7: per-user CSR segment sum: x3[u] = sum_{n in [offs[u], offs[u+1])} x2[n]
// ---------------------------------------------------------------------------
__global__ void k_usersum(const float* __restrict__ x2, const int* __restrict__ offs,
                          float* __restrict__ x3, int U)
{
    int u    = blockIdx.x;
    int lane = threadIdx.x;
    if (u >= U) return;
    int s = offs[u], e = offs[u + 1];
    float acc = 0.0f;
    for (int n = s; n < e; n++) acc += x2[(size_t)n * 64 + lane];
    x3[(size_t)u * 64 + lane] = acc;
}

// ---------------------------------------------------------------------------
// K8: head: out = lrelu(x3[re_index] @ W_f1 + b_f1) @ W_lab + b_lab
// ---------------------------------------------------------------------------
__global__ void k_head(const float* __restrict__ x3, const int* __restrict__ re_index,
                       const float* __restrict__ W_f1, const float* __restrict__ b_f1,
                       const float* __restrict__ W_lab, const float* __restrict__ b_lab,
                       float* __restrict__ out, int U)
{
    int u = blockIdx.x * blockDim.x + threadIdx.x;
    if (u >= U) return;
    int r = re_index[u];
    const float* y = x3 + (size_t)r * 64;
    float yv[64];
    #pragma unroll
    for (int k = 0; k < 64; k++) yv[k] = y[k];
    float o0 = b_lab[0], o1 = b_lab[1];
    for (int j = 0; j < 32; j++) {
        float s = b_f1[j];
        #pragma unroll 8
        for (int k = 0; k < 64; k++) s = fmaf(yv[k], W_f1[k * 32 + j], s);
        s = LRELU(s);
        o0 = fmaf(s, W_lab[j * 2 + 0], o0);
        o1 = fmaf(s, W_lab[j * 2 + 1], o1);
    }
    out[(size_t)u * 2 + 0] = o0;
    out[(size_t)u * 2 + 1] = o1;
}

// ---------------------------------------------------------------------------
extern "C" void kernel_launch(void* const* d_in, const int* in_sizes, int n_in,
                              void* d_out, int out_size, void* d_ws, size_t ws_size,
                              hipStream_t stream)
{
    const float* num_prop = (const float*)d_in[0];
    const float* cat_prop = (const float*)d_in[1];
    const int*   offs     = (const int*)d_in[2];
    const int*   edge     = (const int*)d_in[3];
    const int*   re_index = (const int*)d_in[4];
    const float* W_num    = (const float*)d_in[5];
    const float* b_num    = (const float*)d_in[6];
    const float* W_cat    = (const float*)d_in[7];
    const float* b_cat    = (const float*)d_in[8];
    const float* W_tog    = (const float*)d_in[9];
    const float* b_tog    = (const float*)d_in[10];
    const float* att_l    = (const float*)d_in[11];
    const float* att_r    = (const float*)d_in[12];
    const float* W_f1     = (const float*)d_in[13];
    const float* b_f1     = (const float*)d_in[14];
    const float* W_lab    = (const float*)d_in[15];
    const float* b_lab    = (const float*)d_in[16];

    const int N = in_sizes[0] / 20;
    const int E = in_sizes[3] / 2;
    const int U = in_sizes[4];

    const int* src = edge;       // edge_index[0]
    const int* dst = edge + E;   // edge_index[1]

    // workspace carve-up (4-byte units)
    float* ws = (float*)d_ws;
    size_t off = 0;
    float* x    = ws + off; off += (size_t)N * 64;
    float* h1   = ws + off; off += (size_t)N * 64;
    float* B    = ws + off; off += (size_t)N * 64;   // x2
    float* al   = ws + off; off += N;
    float* ar   = ws + off; off += N;
    float* al2  = ws + off; off += N;
    float* ar2  = ws + off; off += N;
    float* dinv = ws + off; off += N;
    float* x3   = ws + off; off += (size_t)U * 64;
    int*   deg       = (int*)(ws + off); off += N;
    int*   row_start = (int*)(ws + off); off += N;
    int*   cursor    = (int*)(ws + off); off += N;
    int2*  meta0     = (int2*)(ws + off); off += (size_t)E * 2;  // CSR-ordered (src,dst)
    int2*  meta      = (int2*)(ws + off); off += (size_t)E * 2;  // CSR-ordered (src,alpha)
    int*   blockSums = (int*)(ws + off); off += 256;

    hipMemsetAsync(deg, 0, (size_t)N * 4, stream);

    const int nbN4    = (N + 3) / 4;          // wave-per-node kernels, 4 nodes/block
    const int nbScan  = (N + 1023) / 1024;    // <= 256 required by k_scan2
    const int nbE     = (E + 255) / 256;

    k_feat<<<nbN4, 256, 0, stream>>>(num_prop, cat_prop, W_num, b_num, W_cat, b_cat,
                                     W_tog, b_tog, att_l, att_r, x, al, ar, N);
    k_deg<<<nbE, 256, 0, stream>>>(dst, deg, E);

    // CSR build (layer-independent, reused by both gathers)
    k_scan1<<<nbScan, 1024, 0, stream>>>(deg, row_start, blockSums, N);
    k_scan2<<<1, 256, 0, stream>>>(blockSums, nbScan);
    k_scan3<<<(N + 255) / 256, 256, 0, stream>>>(row_start, blockSums, cursor, deg, dinv, N);
    k_fill<<<nbE, 256, 0, stream>>>(src, dst, cursor, meta0, E);

    // ---- FAConv layer 1 (h = h0 = x) ----
    k_alpha<<<nbE, 256, 0, stream>>>(meta0, al, ar, dinv, meta, E);
    k_gather1<<<nbN4, 256, 0, stream>>>(meta, row_start, deg, x, al, ar, dinv,
                                        att_l, att_r, h1, al2, ar2, N);

    // ---- FAConv layer 2 (h = h1, h0 = x) ----
    k_alpha<<<nbE, 256, 0, stream>>>(meta0, al2, ar2, dinv, meta, E);
    k_gather2<<<nbN4, 256, 0, stream>>>(meta, row_start, deg, h1, x, al2, ar2, dinv, B, N);

    // ---- per-user pooling + head ----
    k_usersum<<<U, 64, 0, stream>>>(B, offs, x3, U);
    k_head<<<(U + 255) / 256, 256, 0, stream>>>(x3, re_index, W_f1, b_f1, W_lab, b_lab,
                                                (float*)d_out, U);
}

// Round 5
// 756.711 us; speedup vs baseline: 4.3930x; 1.0951x over previous
//
#include <hip/hip_runtime.h>
#include <hip/hip_bf16.h>

#define LRELU(v) ((v) > 0.0f ? (v) : 0.01f * (v))
#define EPS 0.1f

// ---------------------------------------------------------------------------
// K1: per-node feature MLP, thread-per-node. All weight accesses are
// wave-uniform -> scalar loads (SGPR path); mid[64] in VGPRs; ILP-4 fma chains.
// Fuses al/ar attention dot products. NOTE: inputs loaded with scalar float
// loads — do NOT cast harness-owned d_in pointers to float4* (alignment UB;
// round-4 core dump suspect).
// ---------------------------------------------------------------------------
__global__ void k_feat(const float* __restrict__ num_prop,
                       const float* __restrict__ cat_prop,
                       const float* __restrict__ W_num, const float* __restrict__ b_num,
                       const float* __restrict__ W_cat, const float* __restrict__ b_cat,
                       const float* __restrict__ W_tog, const float* __restrict__ b_tog,
                       const float* __restrict__ att_l, const float* __restrict__ att_r,
                       float* __restrict__ x, float* __restrict__ al, float* __restrict__ ar,
                       int N)
{
    int n = blockIdx.x * blockDim.x + threadIdx.x;
    if (n >= N) return;

    // --- load this node's inputs (plain dword loads, alignment-agnostic) ---
    float num[20], cat[12];
    {
        const float* np_ = num_prop + (size_t)n * 20;
        #pragma unroll
        for (int k = 0; k < 20; k++) num[k] = np_[k];
        const float* cp = cat_prop + (size_t)n * 12;
        #pragma unroll
        for (int k = 0; k < 12; k++) cat[k] = cp[k];
    }

    // --- first layer: mid[0:32] = lrelu(num@Wn+bn), mid[32:64] = lrelu(cat@Wc+bc) ---
    float mid[64];
    #pragma unroll
    for (int j = 0; j < 32; j++) {
        float s = b_num[j];
        #pragma unroll
        for (int k = 0; k < 20; k++) s = fmaf(num[k], W_num[k * 32 + j], s);
        mid[j] = LRELU(s);
    }
    #pragma unroll
    for (int j = 0; j < 32; j++) {
        float s = b_cat[j];
        #pragma unroll
        for (int k = 0; k < 12; k++) s = fmaf(cat[k], W_cat[k * 32 + j], s);
        mid[32 + j] = LRELU(s);
    }

    // --- second layer: x = lrelu(mid @ W_tog + b_tog); fused al/ar dots ---
    float al_acc = 0.0f, ar_acc = 0.0f;
    float* xrow = x + (size_t)n * 64;
    for (int j0 = 0; j0 < 64; j0 += 4) {     // 16 iterations, not unrolled (code size)
        float o[4];
        #pragma unroll
        for (int jj = 0; jj < 4; jj++) {
            int j = j0 + jj;
            float s = b_tog[j];
            #pragma unroll
            for (int k = 0; k < 64; k++) s = fmaf(mid[k], W_tog[k * 64 + j], s);
            s = LRELU(s);
            o[jj] = s;
            al_acc = fmaf(s, att_l[j], al_acc);
            ar_acc = fmaf(s, att_r[j], ar_acc);
        }
        *(float4*)(xrow + j0) = make_float4(o[0], o[1], o[2], o[3]);  // ws: aligned
    }
    al[n] = al_acc;
    ar[n] = ar_acc;
}

// ---------------------------------------------------------------------------
// K2: in-degree histogram over dst (self-loop folded in analytically later)
// ---------------------------------------------------------------------------
__global__ void k_deg(const int* __restrict__ dst, int* __restrict__ deg, int E)
{
    int e = blockIdx.x * blockDim.x + threadIdx.x;
    if (e < E) atomicAdd(&deg[dst[e]], 1);
}

// ---------------------------------------------------------------------------
// CSR build: hierarchical exclusive scan of deg -> row_start, then atomic fill.
// ---------------------------------------------------------------------------
__global__ void k_scan1(const int* __restrict__ deg, int* __restrict__ row_start,
                        int* __restrict__ blockSums, int N)
{
    __shared__ int sh[1024];
    int tid = threadIdx.x;
    int i = blockIdx.x * 1024 + tid;
    int v = (i < N) ? deg[i] : 0;
    sh[tid] = v;
    __syncthreads();
    #pragma unroll
    for (int off = 1; off < 1024; off <<= 1) {
        int t = (tid >= off) ? sh[tid - off] : 0;
        __syncthreads();
        sh[tid] += t;
        __syncthreads();
    }
    if (i < N) row_start[i] = sh[tid] - v;          // exclusive within block
    if (tid == 1023) blockSums[blockIdx.x] = sh[1023];
}

__global__ void k_scan2(int* __restrict__ blockSums, int nb)
{
    __shared__ int sh[256];
    int tid = threadIdx.x;
    int v = (tid < nb) ? blockSums[tid] : 0;
    sh[tid] = v;
    __syncthreads();
    #pragma unroll
    for (int off = 1; off < 256; off <<= 1) {
        int t = (tid >= off) ? sh[tid - off] : 0;
        __syncthreads();
        sh[tid] += t;
        __syncthreads();
    }
    if (tid < nb) blockSums[tid] = sh[tid] - v;     // exclusive
}

// row_start += block offset; init cursor; dinv = rsqrt(deg+1)
__global__ void k_scan3(int* __restrict__ row_start, const int* __restrict__ blockSums,
                        int* __restrict__ cursor, const int* __restrict__ deg,
                        float* __restrict__ dinv, int N)
{
    int i = blockIdx.x * blockDim.x + threadIdx.x;
    if (i >= N) return;
    int rs = row_start[i] + blockSums[i >> 10];
    row_start[i] = rs;
    cursor[i]    = rs;
    dinv[i]      = 1.0f / sqrtf((float)deg[i] + 1.0f);   // +1 self-loop
}

// fill CSR-ordered (src,dst) pairs AND layer-1 alpha in one pass.
// meta0[p] = {src,dst} (kept for the layer-2 alpha pass);
// meta [p] = {src, alpha1} consumed directly by gather1.
__global__ void k_fill(const int* __restrict__ src, const int* __restrict__ dst,
                       int* __restrict__ cursor,
                       const float* __restrict__ al, const float* __restrict__ ar,
                       const float* __restrict__ dinv,
                       int2* __restrict__ meta0, int2* __restrict__ meta, int E)
{
    int e = blockIdx.x * blockDim.x + threadIdx.x;
    if (e >= E) return;
    int s = src[e], d = dst[e];
    int p = atomicAdd(&cursor[d], 1);
    float a = tanhf(al[s] + ar[d]) * dinv[s] * dinv[d];
    meta0[p] = make_int2(s, d);
    meta[p]  = make_int2(s, __float_as_int(a));
}

// ---------------------------------------------------------------------------
// K4: per-edge alpha for layer 2 (edge-parallel, CSR order)
// ---------------------------------------------------------------------------
__global__ void k_alpha(const int2* __restrict__ meta0,
                        const float* __restrict__ al, const float* __restrict__ ar,
                        const float* __restrict__ dinv, int2* __restrict__ meta, int E)
{
    int p = blockIdx.x * blockDim.x + threadIdx.x;
    if (p >= E) return;
    int2 m = meta0[p];
    float a = tanhf(al[m.x] + ar[m.y]) * dinv[m.x] * dinv[m.y];
    meta[p] = make_int2(m.x, __float_as_int(a));
}

// ---------------------------------------------------------------------------
// K5: gather layer 1 (h = h0 = x), fused finalize + al2/ar2 reductions.
// wave-per-node, lane = channel. Unrolled x8: 8 independent row loads in flight.
// ---------------------------------------------------------------------------
__global__ void k_gather1(const int2* __restrict__ meta, const int* __restrict__ row_start,
                          const int* __restrict__ deg,
                          const float* __restrict__ x,
                          const float* __restrict__ al, const float* __restrict__ ar,
                          const float* __restrict__ dinv,
                          const float* __restrict__ att_l, const float* __restrict__ att_r,
                          float* __restrict__ h1, float* __restrict__ al2, float* __restrict__ ar2,
                          int N)
{
    int w    = threadIdx.x >> 6;
    int lane = threadIdx.x & 63;
    int n    = blockIdx.x * 4 + w;
    if (n >= N) return;

    int s0  = row_start[n];
    int cnt = deg[n];

    float acc = 0.0f;
    int j = 0;
    for (; j + 8 <= cnt; j += 8) {
        int2 m[8];
        #pragma unroll
        for (int q = 0; q < 8; q++) m[q] = meta[s0 + j + q];
        float v[8];
        #pragma unroll
        for (int q = 0; q < 8; q++) v[q] = x[(size_t)m[q].x * 64 + lane];
        #pragma unroll
        for (int q = 0; q < 8; q++) acc = fmaf(v[q], __int_as_float(m[q].y), acc);
    }
    for (; j < cnt; j++) {
        int2 m = meta[s0 + j];
        acc = fmaf(x[(size_t)m.x * 64 + lane], __int_as_float(m.y), acc);
    }

    float di    = dinv[n];
    float selfa = tanhf(al[n] + ar[n]) * di * di;
    float v     = acc + (selfa + EPS) * x[(size_t)n * 64 + lane];

    float pl = v * att_l[lane];
    float pr = v * att_r[lane];
    #pragma unroll
    for (int off = 32; off > 0; off >>= 1) {
        pl += __shfl_down(pl, off);
        pr += __shfl_down(pr, off);
    }
    h1[(size_t)n * 64 + lane] = v;
    if (lane == 0) { al2[n] = pl; ar2[n] = pr; }
}

// ---------------------------------------------------------------------------
// K6: gather layer 2 (h = h1, h0 = x), fused finalize + abs-smooth.
// ---------------------------------------------------------------------------
__global__ void k_gather2(const int2* __restrict__ meta, const int* __restrict__ row_start,
                          const int* __restrict__ deg,
                          const float* __restrict__ h1, const float* __restrict__ x,
                          const float* __restrict__ al2, const float* __restrict__ ar2,
                          const float* __restrict__ dinv,
                          float* __restrict__ x2, int N)
{
    int w    = threadIdx.x >> 6;
    int lane = threadIdx.x & 63;
    int n    = blockIdx.x * 4 + w;
    if (n >= N) return;

    int s0  = row_start[n];
    int cnt = deg[n];

    float acc = 0.0f;
    int j = 0;
    for (; j + 8 <= cnt; j += 8) {
        int2 m[8];
        #pragma unroll
        for (int q = 0; q < 8; q++) m[q] = meta[s0 + j + q];
        float v[8];
        #pragma unroll
        for (int q = 0; q < 8; q++) v[q] = h1[(size_t)m[q].x * 64 + lane];
        #pragma unroll
        for (int q = 0; q < 8; q++) acc = fmaf(v[q], __int_as_float(m[q].y), acc);
    }
    for (; j < cnt; j++) {
        int2 m = meta[s0 + j];
        acc = fmaf(h1[(size_t)m.x * 64 + lane], __int_as_float(m.y), acc);
    }

    float di    = dinv[n];
    float selfa = tanhf(al2[n] + ar2[n]) * di * di;
    float v = acc + selfa * h1[(size_t)n * 64 + lane] + EPS * x[(size_t)n * 64 + lane];
    x2[(size_t)n * 64 + lane] = sqrtf(v * v + 1e-8f);
}

// ---------------------------------------------------------------------------
// K7: per-user CSR segment sum: x3[u] = sum_{n in [offs[u], offs[u+1])} x2[n]
// ---------------------------------------------------------------------------
__global__ void k_usersum(const float* __restrict__ x2, const int* __restrict__ offs,
                          float* __restrict__ x3, int U)
{
    int u    = blockIdx.x;
    int lane = threadIdx.x;
    if (u >= U) return;
    int s = offs[u], e = offs[u + 1];
    float acc = 0.0f;
    for (int n = s; n < e; n++) acc += x2[(size_t)n * 64 + lane];
    x3[(size_t)u * 64 + lane] = acc;
}

// ---------------------------------------------------------------------------
// K8: head: out = lrelu(x3[re_index] @ W_f1 + b_f1) @ W_lab + b_lab
// ---------------------------------------------------------------------------
__global__ void k_head(const float* __restrict__ x3, const int* __restrict__ re_index,
                       const float* __restrict__ W_f1, const float* __restrict__ b_f1,
                       const float* __restrict__ W_lab, const float* __restrict__ b_lab,
                       float* __restrict__ out, int U)
{
    int u = blockIdx.x * blockDim.x + threadIdx.x;
    if (u >= U) return;
    int r = re_index[u];
    const float* y = x3 + (size_t)r * 64;
    float yv[64];
    #pragma unroll
    for (int k = 0; k < 64; k++) yv[k] = y[k];
    float o0 = b_lab[0], o1 = b_lab[1];
    for (int j = 0; j < 32; j++) {
        float s = b_f1[j];
        #pragma unroll 8
        for (int k = 0; k < 64; k++) s = fmaf(yv[k], W_f1[k * 32 + j], s);
        s = LRELU(s);
        o0 = fmaf(s, W_lab[j * 2 + 0], o0);
        o1 = fmaf(s, W_lab[j * 2 + 1], o1);
    }
    out[(size_t)u * 2 + 0] = o0;
    out[(size_t)u * 2 + 1] = o1;
}

// ---------------------------------------------------------------------------
extern "C" void kernel_launch(void* const* d_in, const int* in_sizes, int n_in,
                              void* d_out, int out_size, void* d_ws, size_t ws_size,
                              hipStream_t stream)
{
    const float* num_prop = (const float*)d_in[0];
    const float* cat_prop = (const float*)d_in[1];
    const int*   offs     = (const int*)d_in[2];
    const int*   edge     = (const int*)d_in[3];
    const int*   re_index = (const int*)d_in[4];
    const float* W_num    = (const float*)d_in[5];
    const float* b_num    = (const float*)d_in[6];
    const float* W_cat    = (const float*)d_in[7];
    const float* b_cat    = (const float*)d_in[8];
    const float* W_tog    = (const float*)d_in[9];
    const float* b_tog    = (const float*)d_in[10];
    const float* att_l    = (const float*)d_in[11];
    const float* att_r    = (const float*)d_in[12];
    const float* W_f1     = (const float*)d_in[13];
    const float* b_f1     = (const float*)d_in[14];
    const float* W_lab    = (const float*)d_in[15];
    const float* b_lab    = (const float*)d_in[16];

    const int N = in_sizes[0] / 20;
    const int E = in_sizes[3] / 2;
    const int U = in_sizes[4];

    const int* src = edge;       // edge_index[0]
    const int* dst = edge + E;   // edge_index[1]

    // workspace carve-up (4-byte units)
    float* ws = (float*)d_ws;
    size_t off = 0;
    float* x    = ws + off; off += (size_t)N * 64;
    float* h1   = ws + off; off += (size_t)N * 64;
    float* B    = ws + off; off += (size_t)N * 64;   // x2
    float* al   = ws + off; off += N;
    float* ar   = ws + off; off += N;
    float* al2  = ws + off; off += N;
    float* ar2  = ws + off; off += N;
    float* dinv = ws + off; off += N;
    float* x3   = ws + off; off += (size_t)U * 64;
    int*   deg       = (int*)(ws + off); off += N;
    int*   row_start = (int*)(ws + off); off += N;
    int*   cursor    = (int*)(ws + off); off += N;
    int2*  meta0     = (int2*)(ws + off); off += (size_t)E * 2;  // CSR-ordered (src,dst)
    int2*  meta      = (int2*)(ws + off); off += (size_t)E * 2;  // CSR-ordered (src,alpha)
    int*   blockSums = (int*)(ws + off); off += 256;

    hipMemsetAsync(deg, 0, (size_t)N * 4, stream);

    const int nbN4    = (N + 3) / 4;          // wave-per-node kernels, 4 nodes/block
    const int nbScan  = (N + 1023) / 1024;    // <= 256 required by k_scan2
    const int nbE     = (E + 255) / 256;

    k_feat<<<(N + 255) / 256, 256, 0, stream>>>(num_prop, cat_prop, W_num, b_num,
                                                W_cat, b_cat, W_tog, b_tog,
                                                att_l, att_r, x, al, ar, N);
    k_deg<<<nbE, 256, 0, stream>>>(dst, deg, E);

    // CSR build (layer-independent, reused by both gathers)
    k_scan1<<<nbScan, 1024, 0, stream>>>(deg, row_start, blockSums, N);
    k_scan2<<<1, 256, 0, stream>>>(blockSums, nbScan);
    k_scan3<<<(N + 255) / 256, 256, 0, stream>>>(row_start, blockSums, cursor, deg, dinv, N);
    // fill also computes layer-1 alpha inline
    k_fill<<<nbE, 256, 0, stream>>>(src, dst, cursor, al, ar, dinv, meta0, meta, E);

    // ---- FAConv layer 1 (h = h0 = x) ----
    k_gather1<<<nbN4, 256, 0, stream>>>(meta, row_start, deg, x, al, ar, dinv,
                                        att_l, att_r, h1, al2, ar2, N);

    // ---- FAConv layer 2 (h = h1, h0 = x) ----
    k_alpha<<<nbE, 256, 0, stream>>>(meta0, al2, ar2, dinv, meta, E);
    k_gather2<<<nbN4, 256, 0, stream>>>(meta, row_start, deg, h1, x, al2, ar2, dinv, B, N);

    // ---- per-user pooling + head ----
    k_usersum<<<U, 64, 0, stream>>>(B, offs, x3, U);
    k_head<<<(U + 255) / 256, 256, 0, stream>>>(x3, re_index, W_f1, b_f1, W_lab, b_lab,
                                                (float*)d_out, U);
}

// Round 6
// 750.834 us; speedup vs baseline: 4.4274x; 1.0078x over previous
//
#include <hip/hip_runtime.h>
#include <hip/hip_bf16.h>

#define LRELU(v) ((v) > 0.0f ? (v) : 0.01f * (v))
#define EPS 0.1f

// fast tanh via v_exp_f32: exact at +/-inf saturation, ~1e-6 abs err
__device__ __forceinline__ float fast_tanh(float v)
{
    float e = __expf(2.0f * v);
    return 1.0f - 2.0f / (e + 1.0f);
}

// ---------------------------------------------------------------------------
// K1: per-node feature MLP, thread-per-node. All weight accesses are
// wave-uniform -> scalar loads (SGPR path); mid[64] in VGPRs; ILP-4 fma chains.
// Fuses al/ar attention dot products. Inputs loaded with plain dword loads —
// do NOT cast harness-owned d_in pointers to float4* (alignment UB).
// ---------------------------------------------------------------------------
__global__ void k_feat(const float* __restrict__ num_prop,
                       const float* __restrict__ cat_prop,
                       const float* __restrict__ W_num, const float* __restrict__ b_num,
                       const float* __restrict__ W_cat, const float* __restrict__ b_cat,
                       const float* __restrict__ W_tog, const float* __restrict__ b_tog,
                       const float* __restrict__ att_l, const float* __restrict__ att_r,
                       float* __restrict__ x, float* __restrict__ al, float* __restrict__ ar,
                       int N)
{
    int n = blockIdx.x * blockDim.x + threadIdx.x;
    if (n >= N) return;

    float num[20], cat[12];
    {
        const float* np_ = num_prop + (size_t)n * 20;
        #pragma unroll
        for (int k = 0; k < 20; k++) num[k] = np_[k];
        const float* cp = cat_prop + (size_t)n * 12;
        #pragma unroll
        for (int k = 0; k < 12; k++) cat[k] = cp[k];
    }

    float mid[64];
    #pragma unroll
    for (int j = 0; j < 32; j++) {
        float s = b_num[j];
        #pragma unroll
        for (int k = 0; k < 20; k++) s = fmaf(num[k], W_num[k * 32 + j], s);
        mid[j] = LRELU(s);
    }
    #pragma unroll
    for (int j = 0; j < 32; j++) {
        float s = b_cat[j];
        #pragma unroll
        for (int k = 0; k < 12; k++) s = fmaf(cat[k], W_cat[k * 32 + j], s);
        mid[32 + j] = LRELU(s);
    }

    float al_acc = 0.0f, ar_acc = 0.0f;
    float* xrow = x + (size_t)n * 64;
    for (int j0 = 0; j0 < 64; j0 += 4) {     // 16 iterations (code size)
        float o[4];
        #pragma unroll
        for (int jj = 0; jj < 4; jj++) {
            int j = j0 + jj;
            float s = b_tog[j];
            #pragma unroll
            for (int k = 0; k < 64; k++) s = fmaf(mid[k], W_tog[k * 64 + j], s);
            s = LRELU(s);
            o[jj] = s;
            al_acc = fmaf(s, att_l[j], al_acc);
            ar_acc = fmaf(s, att_r[j], ar_acc);
        }
        *(float4*)(xrow + j0) = make_float4(o[0], o[1], o[2], o[3]);  // ws: aligned
    }
    al[n] = al_acc;
    ar[n] = ar_acc;
}

// ---------------------------------------------------------------------------
// K2: in-degree histogram over dst (self-loop folded in analytically later)
// ---------------------------------------------------------------------------
__global__ void k_deg(const int* __restrict__ dst, int* __restrict__ deg, int E)
{
    int e = blockIdx.x * blockDim.x + threadIdx.x;
    if (e < E) atomicAdd(&deg[dst[e]], 1);
}

// ---------------------------------------------------------------------------
// CSR build: hierarchical exclusive scan of deg -> row_start, then atomic fill.
// ---------------------------------------------------------------------------
__global__ void k_scan1(const int* __restrict__ deg, int* __restrict__ row_start,
                        int* __restrict__ blockSums, int N)
{
    __shared__ int sh[1024];
    int tid = threadIdx.x;
    int i = blockIdx.x * 1024 + tid;
    int v = (i < N) ? deg[i] : 0;
    sh[tid] = v;
    __syncthreads();
    #pragma unroll
    for (int off = 1; off < 1024; off <<= 1) {
        int t = (tid >= off) ? sh[tid - off] : 0;
        __syncthreads();
        sh[tid] += t;
        __syncthreads();
    }
    if (i < N) row_start[i] = sh[tid] - v;          // exclusive within block
    if (tid == 1023) blockSums[blockIdx.x] = sh[1023];
}

__global__ void k_scan2(int* __restrict__ blockSums, int nb)
{
    __shared__ int sh[256];
    int tid = threadIdx.x;
    int v = (tid < nb) ? blockSums[tid] : 0;
    sh[tid] = v;
    __syncthreads();
    #pragma unroll
    for (int off = 1; off < 256; off <<= 1) {
        int t = (tid >= off) ? sh[tid - off] : 0;
        __syncthreads();
        sh[tid] += t;
        __syncthreads();
    }
    if (tid < nb) blockSums[tid] = sh[tid] - v;     // exclusive
}

// row_start += block offset; init cursor; pack ald1 = {al, rsqrt(deg+1)}
__global__ void k_scan3(int* __restrict__ row_start, const int* __restrict__ blockSums,
                        int* __restrict__ cursor, const int* __restrict__ deg,
                        const float* __restrict__ al, float2* __restrict__ ald1, int N)
{
    int i = blockIdx.x * blockDim.x + threadIdx.x;
    if (i >= N) return;
    int rs = row_start[i] + blockSums[i >> 10];
    row_start[i] = rs;
    cursor[i]    = rs;
    float dv     = 1.0f / sqrtf((float)deg[i] + 1.0f);   // +1 self-loop
    ald1[i]      = make_float2(al[i], dv);
}

// fill CSR-ordered src ids: one scattered 4B store per edge (slots within a
// row are contiguous -> ~1 dirty line per row instead of 4)
__global__ void k_fill(const int* __restrict__ src, const int* __restrict__ dst,
                       int* __restrict__ cursor, int* __restrict__ srcs, int E)
{
    int e = blockIdx.x * blockDim.x + threadIdx.x;
    if (e >= E) return;
    int d = dst[e];
    int p = atomicAdd(&cursor[d], 1);
    srcs[p] = src[e];
}

// ---------------------------------------------------------------------------
// K5: gather layer 1 (h = h0 = x). alpha computed inline: dst==n so ar[n],
// dinv[n] are wave-uniform; per-edge needs only ald1[s] = {al[s], dinv[s]}
// (one 8B random load, L2-resident array). Unrolled x8. Fused finalize +
// al2/ar2 reductions; epilogue packs ald2 = {al2, dinv}.
// ---------------------------------------------------------------------------
__global__ void k_gather1(const int* __restrict__ srcs, const int* __restrict__ row_start,
                          const int* __restrict__ deg,
                          const float* __restrict__ x,
                          const float2* __restrict__ ald1, const float* __restrict__ ar,
                          const float* __restrict__ att_l, const float* __restrict__ att_r,
                          float* __restrict__ h1, float2* __restrict__ ald2,
                          float* __restrict__ ar2, int N)
{
    int w    = threadIdx.x >> 6;
    int lane = threadIdx.x & 63;
    int n    = blockIdx.x * 4 + w;
    if (n >= N) return;

    int    s0   = row_start[n];
    int    cnt  = deg[n];
    float2 self = ald1[n];          // {al[n], dinv[n]}
    float  di   = self.y;
    float  arn  = ar[n];

    float acc = 0.0f;
    int j = 0;
    for (; j + 8 <= cnt; j += 8) {
        int s[8];
        #pragma unroll
        for (int q = 0; q < 8; q++) s[q] = srcs[s0 + j + q];
        float2 ad[8];
        #pragma unroll
        for (int q = 0; q < 8; q++) ad[q] = ald1[s[q]];
        float v[8];
        #pragma unroll
        for (int q = 0; q < 8; q++) v[q] = x[(size_t)s[q] * 64 + lane];
        #pragma unroll
        for (int q = 0; q < 8; q++) {
            float a = fast_tanh(ad[q].x + arn) * ad[q].y * di;
            acc = fmaf(v[q], a, acc);
        }
    }
    for (; j < cnt; j++) {
        int s = srcs[s0 + j];
        float2 ad = ald1[s];
        float a = fast_tanh(ad.x + arn) * ad.y * di;
        acc = fmaf(x[(size_t)s * 64 + lane], a, acc);
    }

    float selfa = fast_tanh(self.x + arn) * di * di;
    float v     = acc + (selfa + EPS) * x[(size_t)n * 64 + lane];

    float pl = v * att_l[lane];
    float pr = v * att_r[lane];
    #pragma unroll
    for (int off = 32; off > 0; off >>= 1) {
        pl += __shfl_down(pl, off);
        pr += __shfl_down(pr, off);
    }
    h1[(size_t)n * 64 + lane] = v;
    if (lane == 0) { ald2[n] = make_float2(pl, di); ar2[n] = pr; }
}

// ---------------------------------------------------------------------------
// K6: gather layer 2 (h = h1, h0 = x), inline alpha, fused finalize + abs.
// ---------------------------------------------------------------------------
__global__ void k_gather2(const int* __restrict__ srcs, const int* __restrict__ row_start,
                          const int* __restrict__ deg,
                          const float* __restrict__ h1, const float* __restrict__ x,
                          const float2* __restrict__ ald2, const float* __restrict__ ar2,
                          float* __restrict__ x2, int N)
{
    int w    = threadIdx.x >> 6;
    int lane = threadIdx.x & 63;
    int n    = blockIdx.x * 4 + w;
    if (n >= N) return;

    int    s0   = row_start[n];
    int    cnt  = deg[n];
    float2 self = ald2[n];          // {al2[n], dinv[n]}
    float  di   = self.y;
    float  arn  = ar2[n];

    float acc = 0.0f;
    int j = 0;
    for (; j + 8 <= cnt; j += 8) {
        int s[8];
        #pragma unroll
        for (int q = 0; q < 8; q++) s[q] = srcs[s0 + j + q];
        float2 ad[8];
        #pragma unroll
        for (int q = 0; q < 8; q++) ad[q] = ald2[s[q]];
        float v[8];
        #pragma unroll
        for (int q = 0; q < 8; q++) v[q] = h1[(size_t)s[q] * 64 + lane];
        #pragma unroll
        for (int q = 0; q < 8; q++) {
            float a = fast_tanh(ad[q].x + arn) * ad[q].y * di;
            acc = fmaf(v[q], a, acc);
        }
    }
    for (; j < cnt; j++) {
        int s = srcs[s0 + j];
        float2 ad = ald2[s];
        float a = fast_tanh(ad.x + arn) * ad.y * di;
        acc = fmaf(h1[(size_t)s * 64 + lane], a, acc);
    }

    float selfa = fast_tanh(self.x + arn) * di * di;
    float v = acc + selfa * h1[(size_t)n * 64 + lane] + EPS * x[(size_t)n * 64 + lane];
    x2[(size_t)n * 64 + lane] = sqrtf(v * v + 1e-8f);
}

// ---------------------------------------------------------------------------
// K7: per-user CSR segment sum: x3[u] = sum_{n in [offs[u], offs[u+1])} x2[n]
// ---------------------------------------------------------------------------
__global__ void k_usersum(const float* __restrict__ x2, const int* __restrict__ offs,
                          float* __restrict__ x3, int U)
{
    int u    = blockIdx.x;
    int lane = threadIdx.x;
    if (u >= U) return;
    int s = offs[u], e = offs[u + 1];
    float acc = 0.0f;
    for (int n = s; n < e; n++) acc += x2[(size_t)n * 64 + lane];
    x3[(size_t)u * 64 + lane] = acc;
}

// ---------------------------------------------------------------------------
// K8: head: out = lrelu(x3[re_index] @ W_f1 + b_f1) @ W_lab + b_lab
// ---------------------------------------------------------------------------
__global__ void k_head(const float* __restrict__ x3, const int* __restrict__ re_index,
                       const float* __restrict__ W_f1, const float* __restrict__ b_f1,
                       const float* __restrict__ W_lab, const float* __restrict__ b_lab,
                       float* __restrict__ out, int U)
{
    int u = blockIdx.x * blockDim.x + threadIdx.x;
    if (u >= U) return;
    int r = re_index[u];
    const float* y = x3 + (size_t)r * 64;
    float yv[64];
    #pragma unroll
    for (int k = 0; k < 64; k++) yv[k] = y[k];
    float o0 = b_lab[0], o1 = b_lab[1];
    for (int j = 0; j < 32; j++) {
        float s = b_f1[j];
        #pragma unroll 8
        for (int k = 0; k < 64; k++) s = fmaf(yv[k], W_f1[k * 32 + j], s);
        s = LRELU(s);
        o0 = fmaf(s, W_lab[j * 2 + 0], o0);
        o1 = fmaf(s, W_lab[j * 2 + 1], o1);
    }
    out[(size_t)u * 2 + 0] = o0;
    out[(size_t)u * 2 + 1] = o1;
}

// ---------------------------------------------------------------------------
extern "C" void kernel_launch(void* const* d_in, const int* in_sizes, int n_in,
                              void* d_out, int out_size, void* d_ws, size_t ws_size,
                              hipStream_t stream)
{
    const float* num_prop = (const float*)d_in[0];
    const float* cat_prop = (const float*)d_in[1];
    const int*   offs     = (const int*)d_in[2];
    const int*   edge     = (const int*)d_in[3];
    const int*   re_index = (const int*)d_in[4];
    const float* W_num    = (const float*)d_in[5];
    const float* b_num    = (const float*)d_in[6];
    const float* W_cat    = (const float*)d_in[7];
    const float* b_cat    = (const float*)d_in[8];
    const float* W_tog    = (const float*)d_in[9];
    const float* b_tog    = (const float*)d_in[10];
    const float* att_l    = (const float*)d_in[11];
    const float* att_r    = (const float*)d_in[12];
    const float* W_f1     = (const float*)d_in[13];
    const float* b_f1     = (const float*)d_in[14];
    const float* W_lab    = (const float*)d_in[15];
    const float* b_lab    = (const float*)d_in[16];

    const int N = in_sizes[0] / 20;
    const int E = in_sizes[3] / 2;
    const int U = in_sizes[4];

    const int* src = edge;       // edge_index[0]
    const int* dst = edge + E;   // edge_index[1]

    // workspace carve-up (4-byte units; float2 slots 8B-aligned by layout)
    float* ws = (float*)d_ws;
    size_t off = 0;
    float*  x    = ws + off; off += (size_t)N * 64;
    float*  h1   = ws + off; off += (size_t)N * 64;
    float*  B    = ws + off; off += (size_t)N * 64;   // x2
    float2* ald1 = (float2*)(ws + off); off += (size_t)N * 2;
    float2* ald2 = (float2*)(ws + off); off += (size_t)N * 2;
    float*  al   = ws + off; off += N;
    float*  ar   = ws + off; off += N;
    float*  ar2  = ws + off; off += N;
    float*  x3   = ws + off; off += (size_t)U * 64;
    int*    deg       = (int*)(ws + off); off += N;
    int*    row_start = (int*)(ws + off); off += N;
    int*    cursor    = (int*)(ws + off); off += N;
    int*    srcs      = (int*)(ws + off); off += E;
    int*    blockSums = (int*)(ws + off); off += 256;

    hipMemsetAsync(deg, 0, (size_t)N * 4, stream);

    const int nbN4    = (N + 3) / 4;          // wave-per-node kernels, 4 nodes/block
    const int nbScan  = (N + 1023) / 1024;    // <= 256 required by k_scan2
    const int nbE     = (E + 255) / 256;

    k_feat<<<(N + 255) / 256, 256, 0, stream>>>(num_prop, cat_prop, W_num, b_num,
                                                W_cat, b_cat, W_tog, b_tog,
                                                att_l, att_r, x, al, ar, N);
    k_deg<<<nbE, 256, 0, stream>>>(dst, deg, E);

    // CSR build (layer-independent, reused by both gathers)
    k_scan1<<<nbScan, 1024, 0, stream>>>(deg, row_start, blockSums, N);
    k_scan2<<<1, 256, 0, stream>>>(blockSums, nbScan);
    k_scan3<<<(N + 255) / 256, 256, 0, stream>>>(row_start, blockSums, cursor, deg,
                                                 al, ald1, N);
    k_fill<<<nbE, 256, 0, stream>>>(src, dst, cursor, srcs, E);

    // ---- FAConv layer 1 (h = h0 = x), inline alpha ----
    k_gather1<<<nbN4, 256, 0, stream>>>(srcs, row_start, deg, x, ald1, ar,
                                        att_l, att_r, h1, ald2, ar2, N);

    // ---- FAConv layer 2 (h = h1, h0 = x), inline alpha ----
    k_gather2<<<nbN4, 256, 0, stream>>>(srcs, row_start, deg, h1, x, ald2, ar2, B, N);

    // ---- per-user pooling + head ----
    k_usersum<<<U, 64, 0, stream>>>(B, offs, x3, U);
    k_head<<<(U + 255) / 256, 256, 0, stream>>>(x3, re_index, W_f1, b_f1, W_lab, b_lab,
                                                (float*)d_out, U);
}

// Round 7
// 673.698 us; speedup vs baseline: 4.9343x; 1.1145x over previous
//
#include <hip/hip_runtime.h>
#include <hip/hip_bf16.h>

#define LRELU(v) ((v) > 0.0f ? (v) : 0.01f * (v))
#define EPS 0.1f

// fast tanh via v_exp_f32 + v_rcp_f32: ~1e-7 abs err, saturates correctly
__device__ __forceinline__ float fast_tanh(float v)
{
    float e = __expf(2.0f * v);
    return 1.0f - 2.0f * __builtin_amdgcn_rcpf(e + 1.0f);
}

// ---------------------------------------------------------------------------
// K1: per-node feature MLP, thread-per-node. All weight accesses are
// wave-uniform -> scalar loads (SGPR path); mid[64] in VGPRs; ILP-4 fma chains.
// Fuses al/ar attention dot products. Inputs loaded with plain dword loads —
// do NOT cast harness-owned d_in pointers to float4* (alignment UB).
// ---------------------------------------------------------------------------
__global__ void k_feat(const float* __restrict__ num_prop,
                       const float* __restrict__ cat_prop,
                       const float* __restrict__ W_num, const float* __restrict__ b_num,
                       const float* __restrict__ W_cat, const float* __restrict__ b_cat,
                       const float* __restrict__ W_tog, const float* __restrict__ b_tog,
                       const float* __restrict__ att_l, const float* __restrict__ att_r,
                       float* __restrict__ x, float* __restrict__ al, float* __restrict__ ar,
                       int N)
{
    int n = blockIdx.x * blockDim.x + threadIdx.x;
    if (n >= N) return;

    float num[20], cat[12];
    {
        const float* np_ = num_prop + (size_t)n * 20;
        #pragma unroll
        for (int k = 0; k < 20; k++) num[k] = np_[k];
        const float* cp = cat_prop + (size_t)n * 12;
        #pragma unroll
        for (int k = 0; k < 12; k++) cat[k] = cp[k];
    }

    float mid[64];
    #pragma unroll
    for (int j = 0; j < 32; j++) {
        float s = b_num[j];
        #pragma unroll
        for (int k = 0; k < 20; k++) s = fmaf(num[k], W_num[k * 32 + j], s);
        mid[j] = LRELU(s);
    }
    #pragma unroll
    for (int j = 0; j < 32; j++) {
        float s = b_cat[j];
        #pragma unroll
        for (int k = 0; k < 12; k++) s = fmaf(cat[k], W_cat[k * 32 + j], s);
        mid[32 + j] = LRELU(s);
    }

    float al_acc = 0.0f, ar_acc = 0.0f;
    float* xrow = x + (size_t)n * 64;
    for (int j0 = 0; j0 < 64; j0 += 4) {     // 16 iterations (code size)
        float o[4];
        #pragma unroll
        for (int jj = 0; jj < 4; jj++) {
            int j = j0 + jj;
            float s = b_tog[j];
            #pragma unroll
            for (int k = 0; k < 64; k++) s = fmaf(mid[k], W_tog[k * 64 + j], s);
            s = LRELU(s);
            o[jj] = s;
            al_acc = fmaf(s, att_l[j], al_acc);
            ar_acc = fmaf(s, att_r[j], ar_acc);
        }
        *(float4*)(xrow + j0) = make_float4(o[0], o[1], o[2], o[3]);  // ws: aligned
    }
    al[n] = al_acc;
    ar[n] = ar_acc;
}

// ---------------------------------------------------------------------------
// K2: in-degree histogram over dst (self-loop folded in analytically later)
// ---------------------------------------------------------------------------
__global__ void k_deg(const int* __restrict__ dst, int* __restrict__ deg, int E)
{
    int e = blockIdx.x * blockDim.x + threadIdx.x;
    if (e < E) atomicAdd(&deg[dst[e]], 1);
}

// ---------------------------------------------------------------------------
// CSR build over PADDED row lengths ((deg+7)&~7): every row is a whole number
// of 8-edge blocks -> gather has no serial tail. Dummy slots stay -1 (memset).
// ---------------------------------------------------------------------------
__global__ void k_scan1(const int* __restrict__ deg, int* __restrict__ row_start,
                        int* __restrict__ blockSums, int N)
{
    __shared__ int sh[1024];
    int tid = threadIdx.x;
    int i = blockIdx.x * 1024 + tid;
    int v = (i < N) ? ((deg[i] + 7) & ~7) : 0;      // padded length
    sh[tid] = v;
    __syncthreads();
    #pragma unroll
    for (int off = 1; off < 1024; off <<= 1) {
        int t = (tid >= off) ? sh[tid - off] : 0;
        __syncthreads();
        sh[tid] += t;
        __syncthreads();
    }
    if (i < N) row_start[i] = sh[tid] - v;          // exclusive within block
    if (tid == 1023) blockSums[blockIdx.x] = sh[1023];
}

__global__ void k_scan2(int* __restrict__ blockSums, int nb)
{
    __shared__ int sh[256];
    int tid = threadIdx.x;
    int v = (tid < nb) ? blockSums[tid] : 0;
    sh[tid] = v;
    __syncthreads();
    #pragma unroll
    for (int off = 1; off < 256; off <<= 1) {
        int t = (tid >= off) ? sh[tid - off] : 0;
        __syncthreads();
        sh[tid] += t;
        __syncthreads();
    }
    if (tid < nb) blockSums[tid] = sh[tid] - v;     // exclusive
}

// row_start += block offset; init cursor; pack ald1 = {al, rsqrt(deg+1)}
__global__ void k_scan3(int* __restrict__ row_start, const int* __restrict__ blockSums,
                        int* __restrict__ cursor, const int* __restrict__ deg,
                        const float* __restrict__ al, float2* __restrict__ ald1, int N)
{
    int i = blockIdx.x * blockDim.x + threadIdx.x;
    if (i >= N) return;
    int rs = row_start[i] + blockSums[i >> 10];
    row_start[i] = rs;
    cursor[i]    = rs;
    float dv     = 1.0f / sqrtf((float)deg[i] + 1.0f);   // +1 self-loop
    ald1[i]      = make_float2(al[i], dv);
}

// fill CSR-ordered src ids (real edges only; padding slots remain -1)
__global__ void k_fill(const int* __restrict__ src, const int* __restrict__ dst,
                       int* __restrict__ cursor, int* __restrict__ srcs, int E)
{
    int e = blockIdx.x * blockDim.x + threadIdx.x;
    if (e >= E) return;
    int d = dst[e];
    int p = atomicAdd(&cursor[d], 1);
    srcs[p] = src[e];
}

// ---------------------------------------------------------------------------
// K5: gather layer 1 (h = h0 = x). Lane-parallel alpha staging: lane q computes
// alpha for edge q of the chunk (tanh once per chunk in the wave stream), then
// the fma loop gets (s, alpha) via __shfl broadcast. Rows padded to x8 ->
// every row load issues in a batch of 8 (no serial tail). Fused finalize +
// al2/ar2 reductions; epilogue packs ald2 = {al2, dinv}.
// ---------------------------------------------------------------------------
__global__ void k_gather1(const int* __restrict__ srcs, const int* __restrict__ row_start,
                          const int* __restrict__ deg,
                          const float* __restrict__ x,
                          const float2* __restrict__ ald1, const float* __restrict__ ar,
                          const float* __restrict__ att_l, const float* __restrict__ att_r,
                          float* __restrict__ h1, float2* __restrict__ ald2,
                          float* __restrict__ ar2, int N)
{
    int w    = threadIdx.x >> 6;
    int lane = threadIdx.x & 63;
    int n    = blockIdx.x * 4 + w;
    if (n >= N) return;

    int    s0   = row_start[n];
    int    cnt  = deg[n];
    int    cntp = (cnt + 7) & ~7;
    float2 self = ald1[n];          // {al[n], dinv[n]}
    float  di   = self.y;
    float  arn  = ar[n];

    float acc = 0.0f;
    int j = 0;
    while (j < cntp) {
        int chunk = min(cntp - j, 64);     // always a multiple of 8
        int s_mine = -1;
        if (lane < chunk) s_mine = srcs[s0 + j + lane];
        float a_mine = 0.0f;
        if (s_mine >= 0) {
            float2 ad = ald1[s_mine];
            a_mine = fast_tanh(ad.x + arn) * ad.y * di;
        }
        if (s_mine < 0) s_mine = 0;        // dummy: row 0 * alpha 0
        for (int q = 0; q < chunk; q += 8) {
            int sv[8]; float av[8], vv[8];
            #pragma unroll
            for (int t = 0; t < 8; t++) {
                sv[t] = __shfl(s_mine, q + t);
                av[t] = __shfl(a_mine, q + t);
            }
            #pragma unroll
            for (int t = 0; t < 8; t++) vv[t] = x[(size_t)sv[t] * 64 + lane];
            #pragma unroll
            for (int t = 0; t < 8; t++) acc = fmaf(vv[t], av[t], acc);
        }
        j += chunk;
    }

    float selfa = fast_tanh(self.x + arn) * di * di;
    float v     = acc + (selfa + EPS) * x[(size_t)n * 64 + lane];

    float pl = v * att_l[lane];
    float pr = v * att_r[lane];
    #pragma unroll
    for (int off = 32; off > 0; off >>= 1) {
        pl += __shfl_down(pl, off);
        pr += __shfl_down(pr, off);
    }
    h1[(size_t)n * 64 + lane] = v;
    if (lane == 0) { ald2[n] = make_float2(pl, di); ar2[n] = pr; }
}

// ---------------------------------------------------------------------------
// K6: gather layer 2 (h = h1, h0 = x), same staged structure, fused abs.
// ---------------------------------------------------------------------------
__global__ void k_gather2(const int* __restrict__ srcs, const int* __restrict__ row_start,
                          const int* __restrict__ deg,
                          const float* __restrict__ h1, const float* __restrict__ x,
                          const float2* __restrict__ ald2, const float* __restrict__ ar2,
                          float* __restrict__ x2, int N)
{
    int w    = threadIdx.x >> 6;
    int lane = threadIdx.x & 63;
    int n    = blockIdx.x * 4 + w;
    if (n >= N) return;

    int    s0   = row_start[n];
    int    cnt  = deg[n];
    int    cntp = (cnt + 7) & ~7;
    float2 self = ald2[n];          // {al2[n], dinv[n]}
    float  di   = self.y;
    float  arn  = ar2[n];

    float acc = 0.0f;
    int j = 0;
    while (j < cntp) {
        int chunk = min(cntp - j, 64);
        int s_mine = -1;
        if (lane < chunk) s_mine = srcs[s0 + j + lane];
        float a_mine = 0.0f;
        if (s_mine >= 0) {
            float2 ad = ald2[s_mine];
            a_mine = fast_tanh(ad.x + arn) * ad.y * di;
        }
        if (s_mine < 0) s_mine = 0;
        for (int q = 0; q < chunk; q += 8) {
            int sv[8]; float av[8], vv[8];
            #pragma unroll
            for (int t = 0; t < 8; t++) {
                sv[t] = __shfl(s_mine, q + t);
                av[t] = __shfl(a_mine, q + t);
            }
            #pragma unroll
            for (int t = 0; t < 8; t++) vv[t] = h1[(size_t)sv[t] * 64 + lane];
            #pragma unroll
            for (int t = 0; t < 8; t++) acc = fmaf(vv[t], av[t], acc);
        }
        j += chunk;
    }

    float selfa = fast_tanh(self.x + arn) * di * di;
    float v = acc + selfa * h1[(size_t)n * 64 + lane] + EPS * x[(size_t)n * 64 + lane];
    x2[(size_t)n * 64 + lane] = sqrtf(v * v + 1e-8f);
}

// ---------------------------------------------------------------------------
// K7: per-user CSR segment sum: x3[u] = sum_{n in [offs[u], offs[u+1])} x2[n]
// ---------------------------------------------------------------------------
__global__ void k_usersum(const float* __restrict__ x2, const int* __restrict__ offs,
                          float* __restrict__ x3, int U)
{
    int u    = blockIdx.x;
    int lane = threadIdx.x;
    if (u >= U) return;
    int s = offs[u], e = offs[u + 1];
    float acc = 0.0f;
    for (int n = s; n < e; n++) acc += x2[(size_t)n * 64 + lane];
    x3[(size_t)u * 64 + lane] = acc;
}

// ---------------------------------------------------------------------------
// K8: head: out = lrelu(x3[re_index] @ W_f1 + b_f1) @ W_lab + b_lab
// ---------------------------------------------------------------------------
__global__ void k_head(const float* __restrict__ x3, const int* __restrict__ re_index,
                       const float* __restrict__ W_f1, const float* __restrict__ b_f1,
                       const float* __restrict__ W_lab, const float* __restrict__ b_lab,
                       float* __restrict__ out, int U)
{
    int u = blockIdx.x * blockDim.x + threadIdx.x;
    if (u >= U) return;
    int r = re_index[u];
    const float* y = x3 + (size_t)r * 64;
    float yv[64];
    #pragma unroll
    for (int k = 0; k < 64; k++) yv[k] = y[k];
    float o0 = b_lab[0], o1 = b_lab[1];
    for (int j = 0; j < 32; j++) {
        float s = b_f1[j];
        #pragma unroll 8
        for (int k = 0; k < 64; k++) s = fmaf(yv[k], W_f1[k * 32 + j], s);
        s = LRELU(s);
        o0 = fmaf(s, W_lab[j * 2 + 0], o0);
        o1 = fmaf(s, W_lab[j * 2 + 1], o1);
    }
    out[(size_t)u * 2 + 0] = o0;
    out[(size_t)u * 2 + 1] = o1;
}

// ---------------------------------------------------------------------------
extern "C" void kernel_launch(void* const* d_in, const int* in_sizes, int n_in,
                              void* d_out, int out_size, void* d_ws, size_t ws_size,
                              hipStream_t stream)
{
    const float* num_prop = (const float*)d_in[0];
    const float* cat_prop = (const float*)d_in[1];
    const int*   offs     = (const int*)d_in[2];
    const int*   edge     = (const int*)d_in[3];
    const int*   re_index = (const int*)d_in[4];
    const float* W_num    = (const float*)d_in[5];
    const float* b_num    = (const float*)d_in[6];
    const float* W_cat    = (const float*)d_in[7];
    const float* b_cat    = (const float*)d_in[8];
    const float* W_tog    = (const float*)d_in[9];
    const float* b_tog    = (const float*)d_in[10];
    const float* att_l    = (const float*)d_in[11];
    const float* att_r    = (const float*)d_in[12];
    const float* W_f1     = (const float*)d_in[13];
    const float* b_f1     = (const float*)d_in[14];
    const float* W_lab    = (const float*)d_in[15];
    const float* b_lab    = (const float*)d_in[16];

    const int N = in_sizes[0] / 20;
    const int E = in_sizes[3] / 2;
    const int U = in_sizes[4];

    const int* src = edge;       // edge_index[0]
    const int* dst = edge + E;   // edge_index[1]

    const size_t srcsCap = (size_t)E + 7ull * (size_t)N + 64;  // padded CSR capacity

    // workspace carve-up (4-byte units; float2 slots 8B-aligned by layout)
    float* ws = (float*)d_ws;
    size_t off = 0;
    float*  x    = ws + off; off += (size_t)N * 64;
    float*  h1   = ws + off; off += (size_t)N * 64;
    float*  B    = ws + off; off += (size_t)N * 64;   // x2
    float2* ald1 = (float2*)(ws + off); off += (size_t)N * 2;
    float2* ald2 = (float2*)(ws + off); off += (size_t)N * 2;
    float*  al   = ws + off; off += N;
    float*  ar   = ws + off; off += N;
    float*  ar2  = ws + off; off += N;
    float*  x3   = ws + off; off += (size_t)U * 64;
    int*    deg       = (int*)(ws + off); off += N;
    int*    row_start = (int*)(ws + off); off += N;
    int*    cursor    = (int*)(ws + off); off += N;
    int*    srcs      = (int*)(ws + off); off += srcsCap;
    int*    blockSums = (int*)(ws + off); off += 256;

    hipMemsetAsync(deg, 0, (size_t)N * 4, stream);
    hipMemsetAsync(srcs, 0xFF, srcsCap * 4, stream);   // padding slots = -1

    const int nbN4    = (N + 3) / 4;          // wave-per-node kernels, 4 nodes/block
    const int nbScan  = (N + 1023) / 1024;    // <= 256 required by k_scan2
    const int nbE     = (E + 255) / 256;

    k_feat<<<(N + 255) / 256, 256, 0, stream>>>(num_prop, cat_prop, W_num, b_num,
                                                W_cat, b_cat, W_tog, b_tog,
                                                att_l, att_r, x, al, ar, N);
    k_deg<<<nbE, 256, 0, stream>>>(dst, deg, E);

    // padded CSR build (layer-independent, reused by both gathers)
    k_scan1<<<nbScan, 1024, 0, stream>>>(deg, row_start, blockSums, N);
    k_scan2<<<1, 256, 0, stream>>>(blockSums, nbScan);
    k_scan3<<<(N + 255) / 256, 256, 0, stream>>>(row_start, blockSums, cursor, deg,
                                                 al, ald1, N);
    k_fill<<<nbE, 256, 0, stream>>>(src, dst, cursor, srcs, E);

    // ---- FAConv layer 1 (h = h0 = x), staged alpha ----
    k_gather1<<<nbN4, 256, 0, stream>>>(srcs, row_start, deg, x, ald1, ar,
                                        att_l, att_r, h1, ald2, ar2, N);

    // ---- FAConv layer 2 (h = h1, h0 = x), staged alpha ----
    k_gather2<<<nbN4, 256, 0, stream>>>(srcs, row_start, deg, h1, x, ald2, ar2, B, N);

    // ---- per-user pooling + head ----
    k_usersum<<<U, 64, 0, stream>>>(B, offs, x3, U);
    k_head<<<(U + 255) / 256, 256, 0, stream>>>(x3, re_index, W_f1, b_f1, W_lab, b_lab,
                                                (float*)d_out, U);
}

// Round 8
// 590.167 us; speedup vs baseline: 5.6327x; 1.1415x over previous
//
#include <hip/hip_runtime.h>
#include <hip/hip_bf16.h>

#define LRELU(v) ((v) > 0.0f ? (v) : 0.01f * (v))
#define EPS 0.1f

#define BIN_EPB 2048        // edges per k_bin block
#define BIN_CAP 12288       // bucket capacity (expected 8163, +45 sigma headroom)

// fast tanh via v_exp_f32 + v_rcp_f32: ~1e-7 abs err, saturates correctly
__device__ __forceinline__ float fast_tanh(float v)
{
    float e = __expf(2.0f * v);
    return 1.0f - 2.0f * __builtin_amdgcn_rcpf(e + 1.0f);
}

// ---------------------------------------------------------------------------
// K1: per-node feature MLP, thread-per-node. All weight accesses are
// wave-uniform -> scalar loads (SGPR path); mid[64] in VGPRs; ILP-4 fma chains.
// Fuses al/ar attention dot products. Inputs loaded with plain dword loads —
// do NOT cast harness-owned d_in pointers to float4* (alignment UB).
// ---------------------------------------------------------------------------
__global__ void k_feat(const float* __restrict__ num_prop,
                       const float* __restrict__ cat_prop,
                       const float* __restrict__ W_num, const float* __restrict__ b_num,
                       const float* __restrict__ W_cat, const float* __restrict__ b_cat,
                       const float* __restrict__ W_tog, const float* __restrict__ b_tog,
                       const float* __restrict__ att_l, const float* __restrict__ att_r,
                       float* __restrict__ x, float* __restrict__ al, float* __restrict__ ar,
                       int N)
{
    int n = blockIdx.x * blockDim.x + threadIdx.x;
    if (n >= N) return;

    float num[20], cat[12];
    {
        const float* np_ = num_prop + (size_t)n * 20;
        #pragma unroll
        for (int k = 0; k < 20; k++) num[k] = np_[k];
        const float* cp = cat_prop + (size_t)n * 12;
        #pragma unroll
        for (int k = 0; k < 12; k++) cat[k] = cp[k];
    }

    float mid[64];
    #pragma unroll
    for (int j = 0; j < 32; j++) {
        float s = b_num[j];
        #pragma unroll
        for (int k = 0; k < 20; k++) s = fmaf(num[k], W_num[k * 32 + j], s);
        mid[j] = LRELU(s);
    }
    #pragma unroll
    for (int j = 0; j < 32; j++) {
        float s = b_cat[j];
        #pragma unroll
        for (int k = 0; k < 12; k++) s = fmaf(cat[k], W_cat[k * 32 + j], s);
        mid[32 + j] = LRELU(s);
    }

    float al_acc = 0.0f, ar_acc = 0.0f;
    float* xrow = x + (size_t)n * 64;
    for (int j0 = 0; j0 < 64; j0 += 4) {     // 16 iterations (code size)
        float o[4];
        #pragma unroll
        for (int jj = 0; jj < 4; jj++) {
            int j = j0 + jj;
            float s = b_tog[j];
            #pragma unroll
            for (int k = 0; k < 64; k++) s = fmaf(mid[k], W_tog[k * 64 + j], s);
            s = LRELU(s);
            o[jj] = s;
            al_acc = fmaf(s, att_l[j], al_acc);
            ar_acc = fmaf(s, att_r[j], ar_acc);
        }
        *(float4*)(xrow + j0) = make_float4(o[0], o[1], o[2], o[3]);  // ws: aligned
    }
    al[n] = al_acc;
    ar[n] = ar_acc;
}

// ---------------------------------------------------------------------------
// K2: radix partition phase 1. Each block: LDS histogram over dst>>10 buckets,
// one global atomic per (block,bucket) to reserve space, LDS reorder, then
// coalesced chunk writes into bucket regions. Also folds in the deg histogram.
// ---------------------------------------------------------------------------
__global__ void k_bin(const int* __restrict__ src, const int* __restrict__ dst,
                      int* __restrict__ deg, int* __restrict__ bucket_cnt,
                      int2* __restrict__ buckets, int E, int NB)
{
    __shared__ int  hist[256];
    __shared__ int  lbase[256];
    __shared__ int  gbase[256];
    __shared__ int2 stage[BIN_EPB];

    int tid  = threadIdx.x;          // blockDim = 256
    int base = blockIdx.x * BIN_EPB;

    hist[tid] = 0;
    __syncthreads();

    int s[8], d[8], rk[8];
    #pragma unroll
    for (int k = 0; k < 8; k++) {
        int e = base + k * 256 + tid;
        s[k] = -1;
        if (e < E) {
            s[k] = src[e];
            d[k] = dst[e];
            atomicAdd(&deg[d[k]], 1);
            rk[k] = atomicAdd(&hist[d[k] >> 10], 1);
        }
    }
    __syncthreads();

    // exclusive scan of hist -> lbase; reserve global ranges -> gbase
    int v = hist[tid];
    lbase[tid] = v;
    __syncthreads();
    for (int off = 1; off < 256; off <<= 1) {
        int t = (tid >= off) ? lbase[tid - off] : 0;
        __syncthreads();
        lbase[tid] += t;
        __syncthreads();
    }
    int incl = lbase[tid];
    __syncthreads();
    lbase[tid] = incl - v;
    if (tid < NB && v > 0) gbase[tid] = atomicAdd(&bucket_cnt[tid], v);
    __syncthreads();

    // scatter into LDS staging, sorted by bucket
    #pragma unroll
    for (int k = 0; k < 8; k++) {
        if (s[k] >= 0) {
            int b = d[k] >> 10;
            stage[lbase[b] + rk[k]] = make_int2(s[k], d[k]);
        }
    }
    __syncthreads();

    // write out: consecutive staging slots of one bucket -> consecutive global
    int tot = min(BIN_EPB, E - base);
    for (int i = tid; i < tot; i += 256) {
        int2 p = stage[i];
        int b = p.y >> 10;
        buckets[(size_t)b * BIN_CAP + gbase[b] + (i - lbase[b])] = p;
    }
}

// ---------------------------------------------------------------------------
// CSR scan over PADDED row lengths ((deg+7)&~7): every row is a whole number
// of 8-edge blocks -> gather has no serial tail. Dummy slots stay -1 (memset).
// ---------------------------------------------------------------------------
__global__ void k_scan1(const int* __restrict__ deg, int* __restrict__ row_start,
                        int* __restrict__ blockSums, int N)
{
    __shared__ int sh[1024];
    int tid = threadIdx.x;
    int i = blockIdx.x * 1024 + tid;
    int v = (i < N) ? ((deg[i] + 7) & ~7) : 0;      // padded length
    sh[tid] = v;
    __syncthreads();
    #pragma unroll
    for (int off = 1; off < 1024; off <<= 1) {
        int t = (tid >= off) ? sh[tid - off] : 0;
        __syncthreads();
        sh[tid] += t;
        __syncthreads();
    }
    if (i < N) row_start[i] = sh[tid] - v;          // exclusive within block
    if (tid == 1023) blockSums[blockIdx.x] = sh[1023];
}

__global__ void k_scan2(int* __restrict__ blockSums, int nb)
{
    __shared__ int sh[256];
    int tid = threadIdx.x;
    int v = (tid < nb) ? blockSums[tid] : 0;
    sh[tid] = v;
    __syncthreads();
    #pragma unroll
    for (int off = 1; off < 256; off <<= 1) {
        int t = (tid >= off) ? sh[tid - off] : 0;
        __syncthreads();
        sh[tid] += t;
        __syncthreads();
    }
    if (tid < nb) blockSums[tid] = sh[tid] - v;     // exclusive
}

// row_start += block offset; pack ald1 = {al, rsqrt(deg+1)}
__global__ void k_scan3(int* __restrict__ row_start, const int* __restrict__ blockSums,
                        const int* __restrict__ deg,
                        const float* __restrict__ al, float2* __restrict__ ald1, int N)
{
    int i = blockIdx.x * blockDim.x + threadIdx.x;
    if (i >= N) return;
    row_start[i] += blockSums[i >> 10];
    float dv = 1.0f / sqrtf((float)deg[i] + 1.0f);   // +1 self-loop
    ald1[i]  = make_float2(al[i], dv);
}

// ---------------------------------------------------------------------------
// K4: radix partition phase 2. One block per bucket: cursors for the bucket's
// 1024 rows live in LDS (no global atomics); all srcs stores land in this
// block's contiguous ~62 KB window -> lines fill inside one XCD's L2.
// ---------------------------------------------------------------------------
__global__ void k_fill2(const int2* __restrict__ buckets, const int* __restrict__ bucket_cnt,
                        const int* __restrict__ row_start, int* __restrict__ srcs)
{
    __shared__ int cur[1024];
    int b   = blockIdx.x;
    int tid = threadIdx.x;          // blockDim = 1024
    cur[tid] = 0;
    __syncthreads();

    int cnt = bucket_cnt[b];
    const int2* bp = buckets + (size_t)b * BIN_CAP;
    for (int i = tid; i < cnt; i += 1024) {
        int2 p = bp[i];
        int r = p.y & 1023;
        int o = atomicAdd(&cur[r], 1);
        srcs[row_start[p.y] + o] = p.x;
    }
}

// ---------------------------------------------------------------------------
// K5: gather layer 1 (h = h0 = x). Lane-parallel alpha staging; rows padded
// to x8 -> no serial tail. Fused finalize + al2/ar2 reductions; epilogue
// packs ald2 = {al2, dinv}.
// ---------------------------------------------------------------------------
__global__ void k_gather1(const int* __restrict__ srcs, const int* __restrict__ row_start,
                          const int* __restrict__ deg,
                          const float* __restrict__ x,
                          const float2* __restrict__ ald1, const float* __restrict__ ar,
                          const float* __restrict__ att_l, const float* __restrict__ att_r,
                          float* __restrict__ h1, float2* __restrict__ ald2,
                          float* __restrict__ ar2, int N)
{
    int w    = threadIdx.x >> 6;
    int lane = threadIdx.x & 63;
    int n    = blockIdx.x * 4 + w;
    if (n >= N) return;

    int    s0   = row_start[n];
    int    cnt  = deg[n];
    int    cntp = (cnt + 7) & ~7;
    float2 self = ald1[n];          // {al[n], dinv[n]}
    float  di   = self.y;
    float  arn  = ar[n];

    float acc = 0.0f;
    int j = 0;
    while (j < cntp) {
        int chunk = min(cntp - j, 64);     // always a multiple of 8
        int s_mine = -1;
        if (lane < chunk) s_mine = srcs[s0 + j + lane];
        float a_mine = 0.0f;
        if (s_mine >= 0) {
            float2 ad = ald1[s_mine];
            a_mine = fast_tanh(ad.x + arn) * ad.y * di;
        }
        if (s_mine < 0) s_mine = 0;        // dummy: row 0 * alpha 0
        for (int q = 0; q < chunk; q += 8) {
            int sv[8]; float av[8], vv[8];
            #pragma unroll
            for (int t = 0; t < 8; t++) {
                sv[t] = __shfl(s_mine, q + t);
                av[t] = __shfl(a_mine, q + t);
            }
            #pragma unroll
            for (int t = 0; t < 8; t++) vv[t] = x[(size_t)sv[t] * 64 + lane];
            #pragma unroll
            for (int t = 0; t < 8; t++) acc = fmaf(vv[t], av[t], acc);
        }
        j += chunk;
    }

    float selfa = fast_tanh(self.x + arn) * di * di;
    float v     = acc + (selfa + EPS) * x[(size_t)n * 64 + lane];

    float pl = v * att_l[lane];
    float pr = v * att_r[lane];
    #pragma unroll
    for (int off = 32; off > 0; off >>= 1) {
        pl += __shfl_down(pl, off);
        pr += __shfl_down(pr, off);
    }
    h1[(size_t)n * 64 + lane] = v;
    if (lane == 0) { ald2[n] = make_float2(pl, di); ar2[n] = pr; }
}

// ---------------------------------------------------------------------------
// K6: gather layer 2 (h = h1, h0 = x), same staged structure, fused abs.
// ---------------------------------------------------------------------------
__global__ void k_gather2(const int* __restrict__ srcs, const int* __restrict__ row_start,
                          const int* __restrict__ deg,
                          const float* __restrict__ h1, const float* __restrict__ x,
                          const float2* __restrict__ ald2, const float* __restrict__ ar2,
                          float* __restrict__ x2, int N)
{
    int w    = threadIdx.x >> 6;
    int lane = threadIdx.x & 63;
    int n    = blockIdx.x * 4 + w;
    if (n >= N) return;

    int    s0   = row_start[n];
    int    cnt  = deg[n];
    int    cntp = (cnt + 7) & ~7;
    float2 self = ald2[n];          // {al2[n], dinv[n]}
    float  di   = self.y;
    float  arn  = ar2[n];

    float acc = 0.0f;
    int j = 0;
    while (j < cntp) {
        int chunk = min(cntp - j, 64);
        int s_mine = -1;
        if (lane < chunk) s_mine = srcs[s0 + j + lane];
        float a_mine = 0.0f;
        if (s_mine >= 0) {
            float2 ad = ald2[s_mine];
            a_mine = fast_tanh(ad.x + arn) * ad.y * di;
        }
        if (s_mine < 0) s_mine = 0;
        for (int q = 0; q < chunk; q += 8) {
            int sv[8]; float av[8], vv[8];
            #pragma unroll
            for (int t = 0; t < 8; t++) {
                sv[t] = __shfl(s_mine, q + t);
                av[t] = __shfl(a_mine, q + t);
            }
            #pragma unroll
            for (int t = 0; t < 8; t++) vv[t] = h1[(size_t)sv[t] * 64 + lane];
            #pragma unroll
            for (int t = 0; t < 8; t++) acc = fmaf(vv[t], av[t], acc);
        }
        j += chunk;
    }

    float selfa = fast_tanh(self.x + arn) * di * di;
    float v = acc + selfa * h1[(size_t)n * 64 + lane] + EPS * x[(size_t)n * 64 + lane];
    x2[(size_t)n * 64 + lane] = sqrtf(v * v + 1e-8f);
}

// ---------------------------------------------------------------------------
// K7: per-user CSR segment sum: x3[u] = sum_{n in [offs[u], offs[u+1])} x2[n]
// ---------------------------------------------------------------------------
__global__ void k_usersum(const float* __restrict__ x2, const int* __restrict__ offs,
                          float* __restrict__ x3, int U)
{
    int u    = blockIdx.x;
    int lane = threadIdx.x;
    if (u >= U) return;
    int s = offs[u], e = offs[u + 1];
    float acc = 0.0f;
    for (int n = s; n < e; n++) acc += x2[(size_t)n * 64 + lane];
    x3[(size_t)u * 64 + lane] = acc;
}

// ---------------------------------------------------------------------------
// K8: head: out = lrelu(x3[re_index] @ W_f1 + b_f1) @ W_lab + b_lab
// ---------------------------------------------------------------------------
__global__ void k_head(const float* __restrict__ x3, const int* __restrict__ re_index,
                       const float* __restrict__ W_f1, const float* __restrict__ b_f1,
                       const float* __restrict__ W_lab, const float* __restrict__ b_lab,
                       float* __restrict__ out, int U)
{
    int u = blockIdx.x * blockDim.x + threadIdx.x;
    if (u >= U) return;
    int r = re_index[u];
    const float* y = x3 + (size_t)r * 64;
    float yv[64];
    #pragma unroll
    for (int k = 0; k < 64; k++) yv[k] = y[k];
    float o0 = b_lab[0], o1 = b_lab[1];
    for (int j = 0; j < 32; j++) {
        float s = b_f1[j];
        #pragma unroll 8
        for (int k = 0; k < 64; k++) s = fmaf(yv[k], W_f1[k * 32 + j], s);
        s = LRELU(s);
        o0 = fmaf(s, W_lab[j * 2 + 0], o0);
        o1 = fmaf(s, W_lab[j * 2 + 1], o1);
    }
    out[(size_t)u * 2 + 0] = o0;
    out[(size_t)u * 2 + 1] = o1;
}

// ---------------------------------------------------------------------------
extern "C" void kernel_launch(void* const* d_in, const int* in_sizes, int n_in,
                              void* d_out, int out_size, void* d_ws, size_t ws_size,
                              hipStream_t stream)
{
    const float* num_prop = (const float*)d_in[0];
    const float* cat_prop = (const float*)d_in[1];
    const int*   offs     = (const int*)d_in[2];
    const int*   edge     = (const int*)d_in[3];
    const int*   re_index = (const int*)d_in[4];
    const float* W_num    = (const float*)d_in[5];
    const float* b_num    = (const float*)d_in[6];
    const float* W_cat    = (const float*)d_in[7];
    const float* b_cat    = (const float*)d_in[8];
    const float* W_tog    = (const float*)d_in[9];
    const float* b_tog    = (const float*)d_in[10];
    const float* att_l    = (const float*)d_in[11];
    const float* att_r    = (const float*)d_in[12];
    const float* W_f1     = (const float*)d_in[13];
    const float* b_f1     = (const float*)d_in[14];
    const float* W_lab    = (const float*)d_in[15];
    const float* b_lab    = (const float*)d_in[16];

    const int N = in_sizes[0] / 20;
    const int E = in_sizes[3] / 2;
    const int U = in_sizes[4];

    const int* src = edge;       // edge_index[0]
    const int* dst = edge + E;   // edge_index[1]

    const int    NB      = (N + 1023) >> 10;                   // dst buckets
    const size_t srcsCap = (size_t)E + 7ull * (size_t)N + 64;  // padded CSR capacity

    // workspace carve-up (4-byte units; int2/float2 slots 8B-aligned by layout)
    float* ws = (float*)d_ws;
    size_t off = 0;
    float*  x    = ws + off; off += (size_t)N * 64;
    float*  h1   = ws + off; off += (size_t)N * 64;
    float*  B    = ws + off; off += (size_t)N * 64;   // x2
    float2* ald1 = (float2*)(ws + off); off += (size_t)N * 2;
    float2* ald2 = (float2*)(ws + off); off += (size_t)N * 2;
    int2*   buckets = (int2*)(ws + off); off += (size_t)NB * BIN_CAP * 2;
    float*  al   = ws + off; off += N;
    float*  ar   = ws + off; off += N;
    float*  ar2  = ws + off; off += N;
    float*  x3   = ws + off; off += (size_t)U * 64;
    int*    deg        = (int*)(ws + off); off += N;
    int*    row_start  = (int*)(ws + off); off += N;
    int*    bucket_cnt = (int*)(ws + off); off += NB;
    int*    srcs       = (int*)(ws + off); off += srcsCap;
    int*    blockSums  = (int*)(ws + off); off += 256;

    hipMemsetAsync(deg, 0, (size_t)N * 4, stream);
    hipMemsetAsync(bucket_cnt, 0, (size_t)NB * 4, stream);
    hipMemsetAsync(srcs, 0xFF, srcsCap * 4, stream);   // padding slots = -1

    const int nbN4   = (N + 3) / 4;          // wave-per-node kernels, 4 nodes/block
    const int nbScan = (N + 1023) / 1024;    // <= 256 required by k_scan2
    const int nbBin  = (E + BIN_EPB - 1) / BIN_EPB;

    k_feat<<<(N + 255) / 256, 256, 0, stream>>>(num_prop, cat_prop, W_num, b_num,
                                                W_cat, b_cat, W_tog, b_tog,
                                                att_l, att_r, x, al, ar, N);

    // radix partition phase 1 (+ deg histogram folded in)
    k_bin<<<nbBin, 256, 0, stream>>>(src, dst, deg, bucket_cnt, buckets, E, NB);

    // padded CSR offsets
    k_scan1<<<nbScan, 1024, 0, stream>>>(deg, row_start, blockSums, N);
    k_scan2<<<1, 256, 0, stream>>>(blockSums, nbScan);
    k_scan3<<<(N + 255) / 256, 256, 0, stream>>>(row_start, blockSums, deg, al, ald1, N);

    // radix partition phase 2: bucket-local CSR fill (LDS cursors)
    k_fill2<<<NB, 1024, 0, stream>>>(buckets, bucket_cnt, row_start, srcs);

    // ---- FAConv layer 1 (h = h0 = x), staged alpha ----
    k_gather1<<<nbN4, 256, 0, stream>>>(srcs, row_start, deg, x, ald1, ar,
                                        att_l, att_r, h1, ald2, ar2, N);

    // ---- FAConv layer 2 (h = h1, h0 = x), staged alpha ----
    k_gather2<<<nbN4, 256, 0, stream>>>(srcs, row_start, deg, h1, x, ald2, ar2, B, N);

    // ---- per-user pooling + head ----
    k_usersum<<<U, 64, 0, stream>>>(B, offs, x3, U);
    k_head<<<(U + 255) / 256, 256, 0, stream>>>(x3, re_index, W_f1, b_f1, W_lab, b_lab,
                                                (float*)d_out, U);
}